// Round 5
// baseline (842.871 us; speedup 1.0000x reference)
//
// v2 — identical algorithm to v1; resubmission after repeated UnresponsiveContainer infra failures.
#include <hip/hip_runtime.h>
#include <hip/hip_fp16.h>

#define NP 1500      // points per cloud
#define DD 300       // dims
#define DP 304       // padded dims (multiple of 16)
#define VS 1504      // vector stride per batch (pad to multiple of 8)
#define MS 1536      // matrix col stride (halfs)
#define NB 4         // batches
#define KADD 1.8283051e-8f   // eps * ln(1500), eps = (5e-5)^2
#define PADVAL (-60000.0f)

__global__ void k_zero(float* p, int n){
    int i = blockIdx.x*blockDim.x + threadIdx.x;
    if (i < n) p[i] = 0.f;
}

// colsum[b][j] = sum_i x[b][i][j]^2   (grid: 15 chunks x 4 batches x 2 srcs)
__global__ void k_colsum(const float* __restrict__ x, const float* __restrict__ y,
                         float* __restrict__ csx, float* __restrict__ csy){
    __shared__ float acc[DD];
    int b = blockIdx.y, src = blockIdx.z;
    const float* in = (src ? y : x) + (size_t)b*NP*DD + (size_t)blockIdx.x*100*DD;
    float* cs = (src ? csy : csx) + b*DD;
    for (int j = threadIdx.x; j < DD; j += blockDim.x) acc[j] = 0.f;
    __syncthreads();
    for (int t = threadIdx.x; t < 100*DD; t += blockDim.x){
        float v = in[t];
        atomicAdd(&acc[t % DD], v*v);
    }
    __syncthreads();
    for (int j = threadIdx.x; j < DD; j += blockDim.x) atomicAdd(&cs[j], acc[j]);
}

// px[b][i][j] = x^2 / colsum (j<300), 0 in pad cols.  grid.x*256 == NB*NP*DP
__global__ void k_norm(const float* __restrict__ x, const float* __restrict__ y,
                       const float* __restrict__ csx, const float* __restrict__ csy,
                       float* __restrict__ px, float* __restrict__ py){
    int src = blockIdx.y;
    int idx = blockIdx.x*blockDim.x + threadIdx.x;
    const float* in = src ? y : x;
    const float* cs = src ? csy : csx;
    float* o = src ? py : px;
    int j = idx % DP; int t2 = idx / DP; int i = t2 % NP; int b = t2 / NP;
    float v = 0.f;
    if (j < DD){
        float u = in[((size_t)b*NP + i)*DD + j];
        v = u*u / cs[b*DD + j];
    }
    o[idx] = v;
}

// xnrm[b][i] = 0.5 * |px_i|^2  (one wave per row; 12000 waves)
__global__ void k_rownorm(const float* __restrict__ px, const float* __restrict__ py,
                          float* __restrict__ xnrm, float* __restrict__ ynrm){
    int gw = (blockIdx.x*blockDim.x + threadIdx.x) >> 6;
    int lane = threadIdx.x & 63;
    int side = (gw >= NB*NP) ? 1 : 0;
    int rem = gw - side*NB*NP;
    int b = rem / NP, i = rem % NP;
    const float4* row = (const float4*)((side ? py : px) + ((size_t)b*NP + i)*DP);
    float s = 0.f;
    #pragma unroll
    for (int it = 0; it < 2; ++it){
        int j4 = lane + it*64;
        if (j4 < DP/4){
            float4 v = row[j4];
            s += v.x*v.x + v.y*v.y + v.z*v.z + v.w*v.w;
        }
    }
    #pragma unroll
    for (int o = 1; o < 64; o <<= 1) s += __shfl_xor(s, o, 64);
    if (lane == 0) (side ? ynrm : xnrm)[b*VS + i] = 0.5f * s;
}

// 16 GEMMs P[z] = A * B^T, fp32 compute, fp16 store. z = b*4+kind.
// kind 0: px*py^T  1: py*px^T  2: px*px^T  3: py*py^T
__global__ __launch_bounds__(256) void k_gemm(const float* __restrict__ px,
                                              const float* __restrict__ py,
                                              __half* __restrict__ P){
    int z = blockIdx.z, b = z >> 2, kind = z & 3;
    const float* A = (((kind==0)||(kind==2)) ? px : py) + (size_t)b*NP*DP;
    const float* B = (((kind==0)||(kind==3)) ? py : px) + (size_t)b*NP*DP;
    __half* Pz = P + (size_t)z*NP*MS;
    __shared__ float As[16][64];
    __shared__ float Bs[16][64];
    int tid = threadIdx.x, tx = tid & 15, ty = tid >> 4;
    int row0 = blockIdx.x*64, col0 = blockIdx.y*64;
    float acc[4][4] = {};
    int lr = tid >> 2, lk = (tid & 3)*4;
    for (int k0 = 0; k0 < DP; k0 += 16){
        float4 a4 = make_float4(0,0,0,0), b4 = make_float4(0,0,0,0);
        int ar = row0 + lr, br = col0 + lr;
        if (ar < NP) a4 = *(const float4*)(A + (size_t)ar*DP + k0 + lk);
        if (br < NP) b4 = *(const float4*)(B + (size_t)br*DP + k0 + lk);
        As[lk+0][lr] = a4.x; As[lk+1][lr] = a4.y; As[lk+2][lr] = a4.z; As[lk+3][lr] = a4.w;
        Bs[lk+0][lr] = b4.x; Bs[lk+1][lr] = b4.y; Bs[lk+2][lr] = b4.z; Bs[lk+3][lr] = b4.w;
        __syncthreads();
        #pragma unroll
        for (int k = 0; k < 16; ++k){
            float4 av = *(const float4*)&As[k][tx*4];
            float4 bv = *(const float4*)&Bs[k][ty*4];
            acc[0][0] = fmaf(av.x, bv.x, acc[0][0]);
            acc[0][1] = fmaf(av.x, bv.y, acc[0][1]);
            acc[0][2] = fmaf(av.x, bv.z, acc[0][2]);
            acc[0][3] = fmaf(av.x, bv.w, acc[0][3]);
            acc[1][0] = fmaf(av.y, bv.x, acc[1][0]);
            acc[1][1] = fmaf(av.y, bv.y, acc[1][1]);
            acc[1][2] = fmaf(av.y, bv.z, acc[1][2]);
            acc[1][3] = fmaf(av.y, bv.w, acc[1][3]);
            acc[2][0] = fmaf(av.z, bv.x, acc[2][0]);
            acc[2][1] = fmaf(av.z, bv.y, acc[2][1]);
            acc[2][2] = fmaf(av.z, bv.z, acc[2][2]);
            acc[2][3] = fmaf(av.z, bv.w, acc[2][3]);
            acc[3][0] = fmaf(av.w, bv.x, acc[3][0]);
            acc[3][1] = fmaf(av.w, bv.y, acc[3][1]);
            acc[3][2] = fmaf(av.w, bv.z, acc[3][2]);
            acc[3][3] = fmaf(av.w, bv.w, acc[3][3]);
        }
        __syncthreads();
    }
    #pragma unroll
    for (int dm = 0; dm < 4; ++dm){
        int row = row0 + tx*4 + dm;
        if (row < NP){
            int col = col0 + ty*4;
            float v0 = (col+0 < NP) ? acc[dm][0] : PADVAL;
            float v1 = (col+1 < NP) ? acc[dm][1] : PADVAL;
            float v2 = (col+2 < NP) ? acc[dm][2] : PADVAL;
            float v3 = (col+3 < NP) ? acc[dm][3] : PADVAL;
            __half2 h01 = __floats2half2_rn(v0, v1);
            __half2 h23 = __floats2half2_rn(v2, v3);
            uint2 u;
            u.x = *(unsigned int*)&h01;
            u.y = *(unsigned int*)&h23;
            *(uint2*)(Pz + (size_t)row*MS + col) = u;
        }
    }
}

// One phase: job0 (OT update): out0_i = onrm0_i + K + min_j((vnrm0_j - pot0_j) - P[kindA]_ij)
//            job1 (self):      pout1_i = 0.5*(pin1_i + nrm1_i + K + min_j((nrm1_j - pin1_j) - P[kindB]_ij))
// one wave per row; 12000 waves -> 3000 blocks of 256.
__global__ __launch_bounds__(256) void k_sweep(const __half* __restrict__ P, int kindA, int kindB,
        const float* __restrict__ pot0, const float* __restrict__ vnrm0,
        const float* __restrict__ onrm0, float* __restrict__ out0,
        const float* __restrict__ pin1, float* __restrict__ pout1,
        const float* __restrict__ nrm1){
    int gw = (blockIdx.x*blockDim.x + threadIdx.x) >> 6;
    int lane = threadIdx.x & 63;
    int job = (gw >= NB*NP) ? 1 : 0;
    int rem = gw - job*NB*NP;
    int b = rem / NP, i = rem % NP;
    int kind = job ? kindB : kindA;
    const uint4* prow = (const uint4*)(P + ((size_t)(b*4 + kind)*NP + i)*MS);
    const float4* vn4 = (const float4*)((job ? nrm1 : vnrm0) + b*VS);
    const float4* pt4 = (const float4*)((job ? pin1 : pot0) + b*VS);
    float m = 3.0e38f;
    #pragma unroll
    for (int it = 0; it < 3; ++it){
        int j8 = lane + it*64;
        if (j8 < 188){   // ceil(1500/8); pad cols hold -60000 -> never selected
            uint4 pk = prow[j8];
            float4 a0 = vn4[2*j8], a1 = vn4[2*j8+1];
            float4 q0 = pt4[2*j8], q1 = pt4[2*j8+1];
            float2 c0 = __half22float2(*(const __half2*)&pk.x);
            float2 c1 = __half22float2(*(const __half2*)&pk.y);
            float2 c2 = __half22float2(*(const __half2*)&pk.z);
            float2 c3 = __half22float2(*(const __half2*)&pk.w);
            m = fminf(m, (a0.x - q0.x) - c0.x);
            m = fminf(m, (a0.y - q0.y) - c0.y);
            m = fminf(m, (a0.z - q0.z) - c1.x);
            m = fminf(m, (a0.w - q0.w) - c1.y);
            m = fminf(m, (a1.x - q1.x) - c2.x);
            m = fminf(m, (a1.y - q1.y) - c2.y);
            m = fminf(m, (a1.z - q1.z) - c3.x);
            m = fminf(m, (a1.w - q1.w) - c3.y);
        }
    }
    #pragma unroll
    for (int o = 1; o < 64; o <<= 1) m = fminf(m, __shfl_xor(m, o, 64));
    if (lane == 0){
        float base = m + KADD;
        if (job == 0) out0[b*VS + i] = onrm0[b*VS + i] + base;
        else          pout1[b*VS + i] = 0.5f*(pin1[b*VS + i] + nrm1[b*VS + i] + base);
    }
}

__global__ void k_final(const float* __restrict__ f, const float* __restrict__ g,
                        const float* __restrict__ pxx, const float* __restrict__ pyy,
                        float* __restrict__ out){
    __shared__ double red[256];
    double s = 0.0;
    for (int t = threadIdx.x; t < NB*NP; t += 256){
        int b = t / NP, i = t % NP; int o = b*VS + i;
        s += (double)f[o] + (double)g[o] - (double)pxx[o] - (double)pyy[o];
    }
    red[threadIdx.x] = s; __syncthreads();
    for (int w = 128; w > 0; w >>= 1){
        if (threadIdx.x < w) red[threadIdx.x] += red[threadIdx.x + w];
        __syncthreads();
    }
    if (threadIdx.x == 0) out[0] = (float)(red[0] * (4.0/1500.0));
}

extern "C" void kernel_launch(void* const* d_in, const int* in_sizes, int n_in,
                              void* d_out, int out_size, void* d_ws, size_t ws_size,
                              hipStream_t stream) {
    const float* x = (const float*)d_in[0];
    const float* y = (const float*)d_in[1];
    float* out = (float*)d_out;

    float* ws  = (float*)d_ws;
    float* px  = ws;
    float* py  = px + (size_t)NB*NP*DP;
    float* csx = py + (size_t)NB*NP*DP;
    float* csy = csx + NB*DD;
    float* xnrm = csy + NB*DD;
    float* ynrm = xnrm + NB*VS;
    float* fpot = ynrm + NB*VS;
    float* gpot = fpot + NB*VS;
    float* pxx[2]; float* pyy[2];
    pxx[0] = gpot + NB*VS;
    pxx[1] = pxx[0] + NB*VS;
    pyy[0] = pxx[1] + NB*VS;
    pyy[1] = pyy[0] + NB*VS;
    float* smallEnd = pyy[1] + NB*VS;
    __half* P = (__half*)smallEnd;

    // zero colsums + all 8 small vectors (incl. pad entries)
    int nzero = (int)(smallEnd - csx);
    k_zero<<<(nzero + 255)/256, 256, 0, stream>>>(csx, nzero);

    k_colsum<<<dim3(15, NB, 2), 256, 0, stream>>>(x, y, csx, csy);

    int nnorm = NB*NP*DP;               // 1,824,000 (divisible by 256)
    k_norm<<<dim3(nnorm/256, 2), 256, 0, stream>>>(x, y, csx, csy, px, py);

    k_rownorm<<<3000, 256, 0, stream>>>(px, py, xnrm, ynrm);

    k_gemm<<<dim3(24, 24, 16), 256, 0, stream>>>(px, py, P);

    int cxx = 0, cyy = 0;
    for (int t = 0; t < 30; ++t){
        // phase A: f = softmin(Cxy, g) ; pxx self-update
        k_sweep<<<3000, 256, 0, stream>>>(P, 0, 2, gpot, ynrm, xnrm, fpot,
                                          pxx[cxx], pxx[cxx^1], xnrm);
        cxx ^= 1;
        // phase B: g = softmin(Cyx, f) ; pyy self-update
        k_sweep<<<3000, 256, 0, stream>>>(P, 1, 3, fpot, xnrm, ynrm, gpot,
                                          pyy[cyy], pyy[cyy^1], ynrm);
        cyy ^= 1;
    }

    k_final<<<1, 256, 0, stream>>>(fpot, gpot, pxx[cxx], pyy[cyy], out);
}

// Round 6
// 655.571 us; speedup vs baseline: 1.2857x; 1.2857x over previous
//
// v3 — k_gemm replaced by f16-MFMA GEMM (16x16x32_f16, scaled inputs), px/py stored fp16 only.
#include <hip/hip_runtime.h>
#include <hip/hip_fp16.h>

#define NP 1500      // points per cloud
#define DD 300       // dims
#define DP 320       // padded dims (multiple of 32 for K-steps)
#define VS 1504      // vector stride per batch (floats)
#define MS 1536      // matrix col stride (halfs) = 12*128
#define NB 4         // batches
#define KADD 1.8283051e-8f   // eps * ln(1500), eps = (5e-5)^2
#define PADVAL (-60000.0f)
#define SCALE 256.0f
#define SCALE2INV (1.0f/65536.0f)

typedef _Float16 f16x8 __attribute__((ext_vector_type(8)));
typedef float f32x4 __attribute__((ext_vector_type(4)));

__global__ void k_zero(float* p, int n){
    int i = blockIdx.x*blockDim.x + threadIdx.x;
    if (i < n) p[i] = 0.f;
}

// colsum[b][j] = sum_i x[b][i][j]^2   (grid: 15 chunks x 4 batches x 2 srcs)
__global__ void k_colsum(const float* __restrict__ x, const float* __restrict__ y,
                         float* __restrict__ csx, float* __restrict__ csy){
    __shared__ float acc[DD];
    int b = blockIdx.y, src = blockIdx.z;
    const float* in = (src ? y : x) + (size_t)b*NP*DD + (size_t)blockIdx.x*100*DD;
    float* cs = (src ? csy : csx) + b*DD;
    for (int j = threadIdx.x; j < DD; j += blockDim.x) acc[j] = 0.f;
    __syncthreads();
    for (int t = threadIdx.x; t < 100*DD; t += blockDim.x){
        float v = in[t];
        atomicAdd(&acc[t % DD], v*v);
    }
    __syncthreads();
    for (int j = threadIdx.x; j < DD; j += blockDim.x) atomicAdd(&cs[j], acc[j]);
}

// pxh[b][i][j] = f16( SCALE * x^2 / colsum ) (j<300), 0 in pad cols.
__global__ void k_norm(const float* __restrict__ x, const float* __restrict__ y,
                       const float* __restrict__ csx, const float* __restrict__ csy,
                       __half* __restrict__ pxh, __half* __restrict__ pyh){
    int src = blockIdx.y;
    int idx = blockIdx.x*blockDim.x + threadIdx.x;
    const float* in = src ? y : x;
    const float* cs = src ? csy : csx;
    __half* o = src ? pyh : pxh;
    int j = idx % DP; int t2 = idx / DP; int i = t2 % NP; int b = t2 / NP;
    float v = 0.f;
    if (j < DD){
        float u = in[((size_t)b*NP + i)*DD + j];
        v = u*u / cs[b*DD + j] * SCALE;
    }
    o[idx] = __float2half(v);
}

// xnrm[b][i] = 0.5 * |px_i|^2  (one wave per row; 12000 waves) — from scaled fp16
__global__ void k_rownorm(const __half* __restrict__ pxh, const __half* __restrict__ pyh,
                          float* __restrict__ xnrm, float* __restrict__ ynrm){
    int gw = (blockIdx.x*blockDim.x + threadIdx.x) >> 6;
    int lane = threadIdx.x & 63;
    int side = (gw >= NB*NP) ? 1 : 0;
    int rem = gw - side*NB*NP;
    int b = rem / NP, i = rem % NP;
    const __half2* row = (const __half2*)((side ? pyh : pxh) + ((size_t)b*NP + i)*DP);
    float s = 0.f;
    #pragma unroll
    for (int it = 0; it < 3; ++it){
        int j2 = lane + it*64;
        if (j2 < DP/2){
            float2 v = __half22float2(row[j2]);
            s += v.x*v.x + v.y*v.y;
        }
    }
    #pragma unroll
    for (int o = 1; o < 64; o <<= 1) s += __shfl_xor(s, o, 64);
    if (lane == 0) (side ? ynrm : xnrm)[b*VS + i] = s * (0.5f*SCALE2INV);
}

// 16 GEMMs P[z] = (A * B^T)/SCALE^2, f16 MFMA compute (fp32 accum), fp16 store.
// z = b*4+kind. kind 0: px*py^T  1: py*px^T  2: px*px^T  3: py*py^T
// Block: 128x128 tile, 4 waves (2x2 of 64x64), K-step 32, LDS XOR-swizzled.
__global__ __launch_bounds__(256) void k_gemm_mfma(const __half* __restrict__ pxh,
                                                   const __half* __restrict__ pyh,
                                                   __half* __restrict__ P){
    int z = blockIdx.z, b = z >> 2, kind = z & 3;
    const __half* A = (((kind==0)||(kind==2)) ? pxh : pyh) + (size_t)b*NP*DP;
    const __half* B = (((kind==0)||(kind==3)) ? pyh : pxh) + (size_t)b*NP*DP;
    __half* Pz = P + (size_t)z*NP*MS;
    __shared__ __align__(16) char ldsA[8192];   // 128 rows x 32 halfs
    __shared__ __align__(16) char ldsB[8192];
    int tid = threadIdx.x;
    int row0 = blockIdx.x*128, col0 = blockIdx.y*128;
    int lane = tid & 63;
    int w = tid >> 6;
    int wm = (w >> 1)*64, wn = (w & 1)*64;
    int g = tid & 3, rr = tid >> 2;            // staging: granule, row
    int swst = ((g ^ (rr & 3)) << 4);          // staging swizzle (rr&3 == (rr+64)&3)
    int lr = lane & 15;
    int sw = (((lane >> 4) ^ (lane & 3)) << 4); // frag-read swizzle (row&3 == lane&3)

    f32x4 acc[4][4];
    #pragma unroll
    for (int mi = 0; mi < 4; ++mi)
        #pragma unroll
        for (int ni = 0; ni < 4; ++ni)
            acc[mi][ni] = (f32x4){0.f, 0.f, 0.f, 0.f};

    for (int k0 = 0; k0 < DP; k0 += 32){
        uint4 va[2], vb[2];
        #pragma unroll
        for (int rd = 0; rd < 2; ++rd){
            int r = rr + rd*64;
            int ar = row0 + r; if (ar > NP-1) ar = NP-1;   // clamp; garbage rows unused
            int br = col0 + r; if (br > NP-1) br = NP-1;
            va[rd] = *(const uint4*)(A + (size_t)ar*DP + k0 + g*8);
            vb[rd] = *(const uint4*)(B + (size_t)br*DP + k0 + g*8);
        }
        __syncthreads();
        #pragma unroll
        for (int rd = 0; rd < 2; ++rd){
            int r = rr + rd*64;
            *(uint4*)(ldsA + r*64 + swst) = va[rd];
            *(uint4*)(ldsB + r*64 + swst) = vb[rd];
        }
        __syncthreads();
        f16x8 av[4], bv[4];
        #pragma unroll
        for (int mi = 0; mi < 4; ++mi)
            av[mi] = *(const f16x8*)(ldsA + (wm + mi*16 + lr)*64 + sw);
        #pragma unroll
        for (int ni = 0; ni < 4; ++ni)
            bv[ni] = *(const f16x8*)(ldsB + (wn + ni*16 + lr)*64 + sw);
        #pragma unroll
        for (int mi = 0; mi < 4; ++mi)
            #pragma unroll
            for (int ni = 0; ni < 4; ++ni)
                acc[mi][ni] = __builtin_amdgcn_mfma_f32_16x16x32_f16(av[mi], bv[ni], acc[mi][ni], 0, 0, 0);
    }

    // Epilogue: D row = (lane>>4)*4 + v, col = lane&15 within each 16x16 fragment.
    const __half hpad = __float2half(PADVAL);
    int cq = lane >> 4;
    #pragma unroll
    for (int mi = 0; mi < 4; ++mi){
        #pragma unroll
        for (int ni = 0; ni < 4; ++ni){
            int col = col0 + wn + ni*16 + lr;
            bool colok = (col < NP);
            #pragma unroll
            for (int v = 0; v < 4; ++v){
                int row = row0 + wm + mi*16 + cq*4 + v;
                if (row < NP){
                    __half h = colok ? __float2half(acc[mi][ni][v] * SCALE2INV) : hpad;
                    Pz[(size_t)row*MS + col] = h;
                }
            }
        }
    }
}

// One phase: job0 (OT update): out0_i = onrm0_i + K + min_j((vnrm0_j - pot0_j) - P[kindA]_ij)
//            job1 (self):      pout1_i = 0.5*(pin1_i + nrm1_i + K + min_j((nrm1_j - pin1_j) - P[kindB]_ij))
// one wave per row; 12000 waves -> 3000 blocks of 256.
__global__ __launch_bounds__(256) void k_sweep(const __half* __restrict__ P, int kindA, int kindB,
        const float* __restrict__ pot0, const float* __restrict__ vnrm0,
        const float* __restrict__ onrm0, float* __restrict__ out0,
        const float* __restrict__ pin1, float* __restrict__ pout1,
        const float* __restrict__ nrm1){
    int gw = (blockIdx.x*blockDim.x + threadIdx.x) >> 6;
    int lane = threadIdx.x & 63;
    int job = (gw >= NB*NP) ? 1 : 0;
    int rem = gw - job*NB*NP;
    int b = rem / NP, i = rem % NP;
    int kind = job ? kindB : kindA;
    const uint4* prow = (const uint4*)(P + ((size_t)(b*4 + kind)*NP + i)*MS);
    const float4* vn4 = (const float4*)((job ? nrm1 : vnrm0) + b*VS);
    const float4* pt4 = (const float4*)((job ? pin1 : pot0) + b*VS);
    float m = 3.0e38f;
    #pragma unroll
    for (int it = 0; it < 3; ++it){
        int j8 = lane + it*64;
        if (j8 < 188){   // ceil(1500/8); pad cols hold -60000 -> never selected
            uint4 pk = prow[j8];
            float4 a0 = vn4[2*j8], a1 = vn4[2*j8+1];
            float4 q0 = pt4[2*j8], q1 = pt4[2*j8+1];
            float2 c0 = __half22float2(*(const __half2*)&pk.x);
            float2 c1 = __half22float2(*(const __half2*)&pk.y);
            float2 c2 = __half22float2(*(const __half2*)&pk.z);
            float2 c3 = __half22float2(*(const __half2*)&pk.w);
            m = fminf(m, (a0.x - q0.x) - c0.x);
            m = fminf(m, (a0.y - q0.y) - c0.y);
            m = fminf(m, (a0.z - q0.z) - c1.x);
            m = fminf(m, (a0.w - q0.w) - c1.y);
            m = fminf(m, (a1.x - q1.x) - c2.x);
            m = fminf(m, (a1.y - q1.y) - c2.y);
            m = fminf(m, (a1.z - q1.z) - c3.x);
            m = fminf(m, (a1.w - q1.w) - c3.y);
        }
    }
    #pragma unroll
    for (int o = 1; o < 64; o <<= 1) m = fminf(m, __shfl_xor(m, o, 64));
    if (lane == 0){
        float base = m + KADD;
        if (job == 0) out0[b*VS + i] = onrm0[b*VS + i] + base;
        else          pout1[b*VS + i] = 0.5f*(pin1[b*VS + i] + nrm1[b*VS + i] + base);
    }
}

__global__ void k_final(const float* __restrict__ f, const float* __restrict__ g,
                        const float* __restrict__ pxx, const float* __restrict__ pyy,
                        float* __restrict__ out){
    __shared__ double red[256];
    double s = 0.0;
    for (int t = threadIdx.x; t < NB*NP; t += 256){
        int b = t / NP, i = t % NP; int o = b*VS + i;
        s += (double)f[o] + (double)g[o] - (double)pxx[o] - (double)pyy[o];
    }
    red[threadIdx.x] = s; __syncthreads();
    for (int w = 128; w > 0; w >>= 1){
        if (threadIdx.x < w) red[threadIdx.x] += red[threadIdx.x + w];
        __syncthreads();
    }
    if (threadIdx.x == 0) out[0] = (float)(red[0] * (4.0/1500.0));
}

extern "C" void kernel_launch(void* const* d_in, const int* in_sizes, int n_in,
                              void* d_out, int out_size, void* d_ws, size_t ws_size,
                              hipStream_t stream) {
    const float* x = (const float*)d_in[0];
    const float* y = (const float*)d_in[1];
    float* out = (float*)d_out;

    __half* pxh = (__half*)d_ws;                       // NB*NP*DP halfs
    __half* pyh = pxh + (size_t)NB*NP*DP;
    float* csx = (float*)(pyh + (size_t)NB*NP*DP);     // byte off 7,680,000 (16-div)
    float* csy = csx + NB*DD;
    float* xnrm = csy + NB*DD;
    float* ynrm = xnrm + NB*VS;
    float* fpot = ynrm + NB*VS;
    float* gpot = fpot + NB*VS;
    float* pxx[2]; float* pyy[2];
    pxx[0] = gpot + NB*VS;
    pxx[1] = pxx[0] + NB*VS;
    pyy[0] = pxx[1] + NB*VS;
    pyy[1] = pyy[0] + NB*VS;
    float* smallEnd = pyy[1] + NB*VS;
    __half* P = (__half*)smallEnd;                     // 16*NP*MS halfs = 70.8 MB

    // zero colsums + all 8 small vectors (incl. pad entries)
    int nzero = (int)(smallEnd - csx);
    k_zero<<<(nzero + 255)/256, 256, 0, stream>>>(csx, nzero);

    k_colsum<<<dim3(15, NB, 2), 256, 0, stream>>>(x, y, csx, csy);

    int nnorm = NB*NP*DP;               // 1,920,000 (divisible by 256)
    k_norm<<<dim3(nnorm/256, 2), 256, 0, stream>>>(x, y, csx, csy, pxh, pyh);

    k_rownorm<<<3000, 256, 0, stream>>>(pxh, pyh, xnrm, ynrm);

    k_gemm_mfma<<<dim3(12, 12, 16), 256, 0, stream>>>(pxh, pyh, P);

    int cxx = 0, cyy = 0;
    for (int t = 0; t < 30; ++t){
        // phase A: f = softmin(Cxy, g) ; pxx self-update
        k_sweep<<<3000, 256, 0, stream>>>(P, 0, 2, gpot, ynrm, xnrm, fpot,
                                          pxx[cxx], pxx[cxx^1], xnrm);
        cxx ^= 1;
        // phase B: g = softmin(Cyx, f) ; pyy self-update
        k_sweep<<<3000, 256, 0, stream>>>(P, 1, 3, fpot, xnrm, ynrm, gpot,
                                          pyy[cyy], pyy[cyy^1], ynrm);
        cyy ^= 1;
    }

    k_final<<<1, 256, 0, stream>>>(fpot, gpot, pxx[cxx], pyy[cyy], out);
}

// Round 8
// 622.089 us; speedup vs baseline: 1.3549x; 1.0538x over previous
//
// v5 — v4 with the GEMM epilogue write-indexing bug fixed (16 lanes x 8 halfs per 128-half row).
#include <hip/hip_runtime.h>
#include <hip/hip_fp16.h>

#define NP 1500      // points per cloud
#define DD 300       // dims
#define DP 320       // padded dims (multiple of 32 for K-steps)
#define VS 1504      // vector stride per batch (floats)
#define MS 1536      // matrix col stride (halfs) = 12*128
#define NB 4         // batches
#define KADD 1.8283051e-8f   // eps * ln(1500), eps = (5e-5)^2
#define PADVAL (-60000.0f)
#define SCALE 256.0f
#define SCALE2INV (1.0f/65536.0f)

typedef _Float16 f16x8 __attribute__((ext_vector_type(8)));
typedef float f32x4 __attribute__((ext_vector_type(4)));

__global__ void k_zero(float* p, int n){
    int i = blockIdx.x*blockDim.x + threadIdx.x;
    if (i < n) p[i] = 0.f;
}

// colsum[b][j] = sum_i x[b][i][j]^2   (grid: 15 chunks x 4 batches x 2 srcs)
__global__ void k_colsum(const float* __restrict__ x, const float* __restrict__ y,
                         float* __restrict__ csx, float* __restrict__ csy){
    __shared__ float acc[DD];
    int b = blockIdx.y, src = blockIdx.z;
    const float* in = (src ? y : x) + (size_t)b*NP*DD + (size_t)blockIdx.x*100*DD;
    float* cs = (src ? csy : csx) + b*DD;
    for (int j = threadIdx.x; j < DD; j += blockDim.x) acc[j] = 0.f;
    __syncthreads();
    for (int t = threadIdx.x; t < 100*DD; t += blockDim.x){
        float v = in[t];
        atomicAdd(&acc[t % DD], v*v);
    }
    __syncthreads();
    for (int j = threadIdx.x; j < DD; j += blockDim.x) atomicAdd(&cs[j], acc[j]);
}

// pxh[b][i][j] = f16( SCALE * x^2 / colsum ) (j<300), 0 in pad cols.
__global__ void k_norm(const float* __restrict__ x, const float* __restrict__ y,
                       const float* __restrict__ csx, const float* __restrict__ csy,
                       __half* __restrict__ pxh, __half* __restrict__ pyh){
    int src = blockIdx.y;
    int idx = blockIdx.x*blockDim.x + threadIdx.x;
    const float* in = src ? y : x;
    const float* cs = src ? csy : csx;
    __half* o = src ? pyh : pxh;
    int j = idx % DP; int t2 = idx / DP; int i = t2 % NP; int b = t2 / NP;
    float v = 0.f;
    if (j < DD){
        float u = in[((size_t)b*NP + i)*DD + j];
        v = u*u / cs[b*DD + j] * SCALE;
    }
    o[idx] = __float2half(v);
}

// init small vectors from scaled fp16 rows: side0 -> psxx0 = xnrm; side1 -> u = psyy0 = ynrm
__global__ void k_rownorm(const __half* __restrict__ pxh, const __half* __restrict__ pyh,
                          float* __restrict__ psxx0, float* __restrict__ uvec,
                          float* __restrict__ psyy0){
    int gw = (blockIdx.x*blockDim.x + threadIdx.x) >> 6;
    int lane = threadIdx.x & 63;
    int side = (gw >= NB*NP) ? 1 : 0;
    int rem = gw - side*NB*NP;
    int b = rem / NP, i = rem % NP;
    const __half2* row = (const __half2*)((side ? pyh : pxh) + ((size_t)b*NP + i)*DP);
    float s = 0.f;
    #pragma unroll
    for (int it = 0; it < 3; ++it){
        int j2 = lane + it*64;
        if (j2 < DP/2){
            float2 v = __half22float2(row[j2]);
            s += v.x*v.x + v.y*v.y;
        }
    }
    #pragma unroll
    for (int o = 1; o < 64; o <<= 1) s += __shfl_xor(s, o, 64);
    if (lane == 0){
        float val = s * (0.5f*SCALE2INV);
        int o = b*VS + i;
        if (side){ uvec[o] = val; psyy0[o] = val; }
        else     { psxx0[o] = val; }
    }
}

// 16 GEMMs P[z] = (A * B^T)/SCALE^2, f16 MFMA compute (fp32 accum), fp16 store.
// z = b*4+kind. kind 0: px*py^T  1: py*px^T  2: px*px^T  3: py*py^T
// Block: 128x128 tile, 4 waves (2x2 of 64x64), K-step 32; coalesced epilogue via LDS.
__global__ __launch_bounds__(256) void k_gemm_mfma(const __half* __restrict__ pxh,
                                                   const __half* __restrict__ pyh,
                                                   __half* __restrict__ P){
    int z = blockIdx.z, b = z >> 2, kind = z & 3;
    const __half* A = (((kind==0)||(kind==2)) ? pxh : pyh) + (size_t)b*NP*DP;
    const __half* B = (((kind==0)||(kind==3)) ? pyh : pxh) + (size_t)b*NP*DP;
    __half* Pz = P + (size_t)z*NP*MS;
    __shared__ __align__(16) char ldsA[8192];   // 128 rows x 32 halfs
    __shared__ __align__(16) char ldsB[8192];
    __shared__ __align__(16) __half ldsO[128*128];  // 32 KB output tile
    int tid = threadIdx.x;
    int row0 = blockIdx.x*128, col0 = blockIdx.y*128;
    int lane = tid & 63;
    int w = tid >> 6;
    int wm = (w >> 1)*64, wn = (w & 1)*64;
    int g = tid & 3, rr = tid >> 2;            // staging: granule, row
    int swst = ((g ^ (rr & 3)) << 4);          // staging swizzle (rr&3 == (rr+64)&3)
    int lr = lane & 15;
    int sw = (((lane >> 4) ^ (lane & 3)) << 4); // frag-read swizzle (row&3 == lane&3)

    f32x4 acc[4][4];
    #pragma unroll
    for (int mi = 0; mi < 4; ++mi)
        #pragma unroll
        for (int ni = 0; ni < 4; ++ni)
            acc[mi][ni] = (f32x4){0.f, 0.f, 0.f, 0.f};

    for (int k0 = 0; k0 < DP; k0 += 32){
        uint4 va[2], vb[2];
        #pragma unroll
        for (int rd = 0; rd < 2; ++rd){
            int r = rr + rd*64;
            int ar = row0 + r; if (ar > NP-1) ar = NP-1;   // clamp; garbage rows unused
            int br = col0 + r; if (br > NP-1) br = NP-1;
            va[rd] = *(const uint4*)(A + (size_t)ar*DP + k0 + g*8);
            vb[rd] = *(const uint4*)(B + (size_t)br*DP + k0 + g*8);
        }
        __syncthreads();
        #pragma unroll
        for (int rd = 0; rd < 2; ++rd){
            int r = rr + rd*64;
            *(uint4*)(ldsA + r*64 + swst) = va[rd];
            *(uint4*)(ldsB + r*64 + swst) = vb[rd];
        }
        __syncthreads();
        f16x8 av[4], bv[4];
        #pragma unroll
        for (int mi = 0; mi < 4; ++mi)
            av[mi] = *(const f16x8*)(ldsA + (wm + mi*16 + lr)*64 + sw);
        #pragma unroll
        for (int ni = 0; ni < 4; ++ni)
            bv[ni] = *(const f16x8*)(ldsB + (wn + ni*16 + lr)*64 + sw);
        #pragma unroll
        for (int mi = 0; mi < 4; ++mi)
            #pragma unroll
            for (int ni = 0; ni < 4; ++ni)
                acc[mi][ni] = __builtin_amdgcn_mfma_f32_16x16x32_f16(av[mi], bv[ni], acc[mi][ni], 0, 0, 0);
    }

    // Stage D tile in LDS (fragment layout: row = (lane>>4)*4 + v, col = lane&15)
    __syncthreads();
    const __half hpad = __float2half(PADVAL);
    int cq = lane >> 4;
    #pragma unroll
    for (int mi = 0; mi < 4; ++mi){
        #pragma unroll
        for (int ni = 0; ni < 4; ++ni){
            int lcol = wn + ni*16 + lr;
            bool colok = (col0 + lcol < NP);
            #pragma unroll
            for (int v = 0; v < 4; ++v){
                int lrow = wm + mi*16 + cq*4 + v;
                ldsO[lrow*128 + lcol] = colok ? __float2half(acc[mi][ni][v] * SCALE2INV) : hpad;
            }
        }
    }
    __syncthreads();
    // Coalesced row writes: 16 lanes x 8 halfs (uint4) cover one 128-half row; 8 passes.
    int cl = (tid & 15) * 8;
    int rbase = tid >> 4;   // 0..15
    #pragma unroll
    for (int it = 0; it < 8; ++it){
        int r = rbase + it*16;
        int grow = row0 + r;
        if (grow < NP){
            uint4 vv = *(const uint4*)(ldsO + r*128 + cl);
            *(uint4*)(Pz + (size_t)grow*MS + col0 + cl) = vv;
        }
    }
}

// Dual-variable sweep. job0: outA_i = -(min_j(inA_j - P[kindA]_ij) + K)
//                      job1: psout_i = 0.5*(psin_i - min_j(psin_j - P[kindB]_ij) - K)
// one wave per row; 12000 waves -> 3000 blocks of 256.
__global__ __launch_bounds__(256) void k_sweep(const __half* __restrict__ P, int kindA, int kindB,
        const float* __restrict__ inA, float* __restrict__ outA,
        const float* __restrict__ psin, float* __restrict__ psout){
    int gw = (blockIdx.x*blockDim.x + threadIdx.x) >> 6;
    int lane = threadIdx.x & 63;
    int job = (gw >= NB*NP) ? 1 : 0;
    int rem = gw - job*NB*NP;
    int b = rem / NP, i = rem % NP;
    int kind = job ? kindB : kindA;
    const uint4* prow = (const uint4*)(P + ((size_t)(b*4 + kind)*NP + i)*MS);
    const float4* a4 = (const float4*)((job ? psin : inA) + b*VS);
    float m = 3.0e38f;
    #pragma unroll
    for (int it = 0; it < 3; ++it){
        int j8 = lane + it*64;
        if (j8 < 188){   // ceil(1500/8); pad cols hold -60000 -> never selected
            uint4 pk = prow[j8];
            float4 a0 = a4[2*j8], a1 = a4[2*j8+1];
            float2 c0 = __half22float2(*(const __half2*)&pk.x);
            float2 c1 = __half22float2(*(const __half2*)&pk.y);
            float2 c2 = __half22float2(*(const __half2*)&pk.z);
            float2 c3 = __half22float2(*(const __half2*)&pk.w);
            m = fminf(m, a0.x - c0.x);
            m = fminf(m, a0.y - c0.y);
            m = fminf(m, a0.z - c1.x);
            m = fminf(m, a0.w - c1.y);
            m = fminf(m, a1.x - c2.x);
            m = fminf(m, a1.y - c2.y);
            m = fminf(m, a1.z - c3.x);
            m = fminf(m, a1.w - c3.y);
        }
    }
    #pragma unroll
    for (int o = 1; o < 64; o <<= 1) m = fminf(m, __shfl_xor(m, o, 64));
    if (lane == 0){
        int o = b*VS + i;
        if (job == 0) outA[o] = -(m + KADD);
        else          psout[o] = 0.5f*(psin[o] - m - KADD);
    }
}

// S = (4/1500) * sum_b,i (psxx + psyy - fs - u)   [xnrm/ynrm means cancel]
__global__ void k_final(const float* __restrict__ fs, const float* __restrict__ u,
                        const float* __restrict__ psxx, const float* __restrict__ psyy,
                        float* __restrict__ out){
    __shared__ double red[256];
    double s = 0.0;
    for (int t = threadIdx.x; t < NB*NP; t += 256){
        int b = t / NP, i = t % NP; int o = b*VS + i;
        s += (double)psxx[o] + (double)psyy[o] - (double)fs[o] - (double)u[o];
    }
    red[threadIdx.x] = s; __syncthreads();
    for (int w = 128; w > 0; w >>= 1){
        if (threadIdx.x < w) red[threadIdx.x] += red[threadIdx.x + w];
        __syncthreads();
    }
    if (threadIdx.x == 0) out[0] = (float)(red[0] * (4.0/1500.0));
}

extern "C" void kernel_launch(void* const* d_in, const int* in_sizes, int n_in,
                              void* d_out, int out_size, void* d_ws, size_t ws_size,
                              hipStream_t stream) {
    const float* x = (const float*)d_in[0];
    const float* y = (const float*)d_in[1];
    float* out = (float*)d_out;

    __half* pxh = (__half*)d_ws;                       // NB*NP*DP halfs
    __half* pyh = pxh + (size_t)NB*NP*DP;
    float* csx = (float*)(pyh + (size_t)NB*NP*DP);     // byte off 7,680,000 (16-div)
    float* csy = csx + NB*DD;
    float* fs  = csy + NB*DD;
    float* uv  = fs + NB*VS;
    float* psxx[2]; float* psyy[2];
    psxx[0] = uv + NB*VS;
    psxx[1] = psxx[0] + NB*VS;
    psyy[0] = psxx[1] + NB*VS;
    psyy[1] = psyy[0] + NB*VS;
    float* smallEnd = psyy[1] + NB*VS;
    __half* P = (__half*)smallEnd;                     // 16*NP*MS halfs = 73.7 MB

    // zero colsums + all 6 small vectors (incl. pad entries)
    int nzero = (int)(smallEnd - csx);
    k_zero<<<(nzero + 255)/256, 256, 0, stream>>>(csx, nzero);

    k_colsum<<<dim3(15, NB, 2), 256, 0, stream>>>(x, y, csx, csy);

    int nnorm = NB*NP*DP;               // 1,920,000 (divisible by 256)
    k_norm<<<dim3(nnorm/256, 2), 256, 0, stream>>>(x, y, csx, csy, pxh, pyh);

    k_rownorm<<<3000, 256, 0, stream>>>(pxh, pyh, psxx[0], uv, psyy[0]);

    k_gemm_mfma<<<dim3(12, 12, 16), 256, 0, stream>>>(pxh, pyh, P);

    int cxx = 0, cyy = 0;
    for (int t = 0; t < 30; ++t){
        // phase A: fs = -(rowmin(P0, u)+K) ; psxx self-update
        k_sweep<<<3000, 256, 0, stream>>>(P, 0, 2, uv, fs, psxx[cxx], psxx[cxx^1]);
        cxx ^= 1;
        // phase B: u = -(rowmin(P1, fs)+K) ; psyy self-update
        k_sweep<<<3000, 256, 0, stream>>>(P, 1, 3, fs, uv, psyy[cyy], psyy[cyy^1]);
        cyy ^= 1;
    }

    k_final<<<1, 256, 0, stream>>>(fs, uv, psxx[cxx], psyy[cyy], out);
}

// Round 9
// 481.725 us; speedup vs baseline: 1.7497x; 1.2914x over previous
//
// v6 — persistent Sinkhorn kernel (DIY grid barrier + per-subsystem bitwise freeze),
// tiled P layout, GEMM with triangle+transpose-write (kind1/2/3 halved), deterministic colsum.
#include <hip/hip_runtime.h>
#include <hip/hip_fp16.h>

#define NP 1500
#define DD 300
#define DP 320              // padded dims (mult of 32)
#define VSZ 1536            // vector stride per batch (floats)
#define NB 4
#define TILE 16384          // halfs per 128x128 tile
#define TSZ (1536*1536)     // halfs per P slot
#define NBLK 512
#define KADD 1.8283051e-8f  // eps * ln(1500), eps = (5e-5)^2
#define PADVAL (-60000.0f)
#define SCALE 256.0f
#define SCALE2INV (1.0f/65536.0f)

typedef _Float16 f16x8 __attribute__((ext_vector_type(8)));
typedef float f32x4 __attribute__((ext_vector_type(4)));

__global__ void k_zero(float* p, int n){
    int i = blockIdx.x*blockDim.x + threadIdx.x;
    if (i < n) p[i] = 0.f;
}

// ---- deterministic column sums (2-stage, no float atomics) ----
__global__ __launch_bounds__(256) void k_colsum_p1(const float* __restrict__ x, const float* __restrict__ y,
                                                   float* __restrict__ partial){
    int rc = blockIdx.x, b = blockIdx.y, src = blockIdx.z;
    const float* in = (src ? y : x) + ((size_t)b*NP + rc*125)*DD;
    int tid = threadIdx.x;
    float s0 = 0.f, s1 = 0.f;
    #pragma unroll 4
    for (int r = 0; r < 125; ++r){
        float v0 = in[r*DD + tid];
        s0 = fmaf(v0, v0, s0);
        if (tid < 44){
            float v1 = in[r*DD + 256 + tid];
            s1 = fmaf(v1, v1, s1);
        }
    }
    float* po = partial + (((size_t)rc*NB + b)*2 + src)*DD;
    po[tid] = s0;
    if (tid < 44) po[256 + tid] = s1;
}

__global__ void k_colsum_p2(const float* __restrict__ partial,
                            float* __restrict__ csx, float* __restrict__ csy){
    int idx = blockIdx.x*256 + threadIdx.x;
    if (idx >= NB*2*DD) return;
    int c = idx % DD; int t = idx / DD; int src = t & 1; int b = t >> 1;
    float s = 0.f;
    #pragma unroll
    for (int rc = 0; rc < 12; ++rc)
        s += partial[(((size_t)rc*NB + b)*2 + src)*DD + c];
    (src ? csy : csx)[b*DD + c] = s;
}

// ---- fused normalize (fp16, scaled) + row-norm init of small vectors ----
__global__ __launch_bounds__(256) void k_normrow(const float* __restrict__ x, const float* __restrict__ y,
        const float* __restrict__ csx, const float* __restrict__ csy,
        __half* __restrict__ pxh, __half* __restrict__ pyh,
        float* __restrict__ psxx0, float* __restrict__ uvv, float* __restrict__ psyy0){
    int i = blockIdx.x, b = blockIdx.y, src = blockIdx.z;
    const float* in = (src ? y : x) + ((size_t)b*NP + i)*DD;
    const float* cs = (src ? csy : csx) + b*DD;
    __half* oph = (src ? pyh : pxh) + ((size_t)b*NP + i)*DP;
    int tid = threadIdx.x;
    float s;
    {
        float u = in[tid];
        float vu = u*u / cs[tid];
        oph[tid] = __float2half(vu * SCALE);
        s = vu*vu;
    }
    if (tid < 64){
        int c = 256 + tid;
        float h = 0.f, vu = 0.f;
        if (c < DD){
            float u = in[c];
            vu = u*u / cs[c];
            h = vu * SCALE;
        }
        oph[c] = __float2half(h);
        s += vu*vu;
    }
    #pragma unroll
    for (int o2 = 1; o2 < 64; o2 <<= 1) s += __shfl_xor(s, o2, 64);
    __shared__ float sred[4];
    if ((tid & 63) == 0) sred[tid>>6] = s;
    __syncthreads();
    if (tid == 0){
        float val = 0.5f*(sred[0]+sred[1]+sred[2]+sred[3]);
        int o = b*VSZ + i;
        if (src){ uvv[o] = val; psyy0[o] = val; }
        else    { psxx0[o] = val; }
    }
}

// ---- MFMA GEMM, tiled-P output, triangle + transpose-write ----
// z = b*3 + kidx; kidx -> kind {0,2,3}. kind0 writes slot0(bx,by) + slot1(by,bx).
// kind2/3: compute by<=bx only; write slot(bx,by) + transposed slot(by,bx).
__global__ __launch_bounds__(256) void k_gemm_mfma(const __half* __restrict__ pxh,
                                                   const __half* __restrict__ pyh,
                                                   __half* __restrict__ P){
    int z = blockIdx.z; int b = z/3; int kidx = z - b*3;
    int kind = (kidx==0) ? 0 : ((kidx==1) ? 2 : 3);
    int bx = blockIdx.x, by = blockIdx.y;
    if (kind != 0 && by > bx) return;
    const __half* A = (((kind==0)||(kind==2)) ? pxh : pyh) + (size_t)b*NP*DP;
    const __half* B = (((kind==0)||(kind==3)) ? pyh : pxh) + (size_t)b*NP*DP;

    __shared__ __align__(16) char smem[128*136*2];   // 34816 B; staging overlaps epilogue tile
    char* ldsA = smem;                 // 128 x 32 halfs = 8192 B
    char* ldsB = smem + 8192;          // 8192 B
    __half* ldsO = (__half*)smem;      // 128 rows x 136 halfs (epilogue)

    int tid = threadIdx.x;
    int row0 = bx*128, col0 = by*128;
    int lane = tid & 63;
    int w = tid >> 6;
    int wm = (w >> 1)*64, wn = (w & 1)*64;
    int g = tid & 3, rr = tid >> 2;
    int swst = ((g ^ (rr & 3)) << 4);
    int lr = lane & 15;
    int sw = (((lane >> 4) ^ (lane & 3)) << 4);

    f32x4 acc[4][4];
    #pragma unroll
    for (int mi = 0; mi < 4; ++mi)
        #pragma unroll
        for (int ni = 0; ni < 4; ++ni)
            acc[mi][ni] = (f32x4){0.f, 0.f, 0.f, 0.f};

    for (int k0 = 0; k0 < DP; k0 += 32){
        uint4 va[2], vb[2];
        #pragma unroll
        for (int rd = 0; rd < 2; ++rd){
            int r = rr + rd*64;
            int ar = row0 + r; if (ar > NP-1) ar = NP-1;
            int br = col0 + r; if (br > NP-1) br = NP-1;
            va[rd] = *(const uint4*)(A + (size_t)ar*DP + k0 + g*8);
            vb[rd] = *(const uint4*)(B + (size_t)br*DP + k0 + g*8);
        }
        __syncthreads();
        #pragma unroll
        for (int rd = 0; rd < 2; ++rd){
            int r = rr + rd*64;
            *(uint4*)(ldsA + r*64 + swst) = va[rd];
            *(uint4*)(ldsB + r*64 + swst) = vb[rd];
        }
        __syncthreads();
        f16x8 av[4], bv[4];
        #pragma unroll
        for (int mi = 0; mi < 4; ++mi)
            av[mi] = *(const f16x8*)(ldsA + (wm + mi*16 + lr)*64 + sw);
        #pragma unroll
        for (int ni = 0; ni < 4; ++ni)
            bv[ni] = *(const f16x8*)(ldsB + (wn + ni*16 + lr)*64 + sw);
        #pragma unroll
        for (int mi = 0; mi < 4; ++mi)
            #pragma unroll
            for (int ni = 0; ni < 4; ++ni)
                acc[mi][ni] = __builtin_amdgcn_mfma_f32_16x16x32_f16(av[mi], bv[ni], acc[mi][ni], 0, 0, 0);
    }

    int cq = lane >> 4;
    // ---- direct tile: stage (frag row = wm+mi*16+cq*4+v, col = wn+ni*16+lr) ----
    __syncthreads();
    #pragma unroll
    for (int mi = 0; mi < 4; ++mi)
        #pragma unroll
        for (int ni = 0; ni < 4; ++ni){
            int lcol = wn + ni*16 + lr;
            bool colok = (col0 + lcol) < NP;
            #pragma unroll
            for (int v = 0; v < 4; ++v){
                int lrow = wm + mi*16 + cq*4 + v;
                ldsO[lrow*136 + lcol] = __float2half(colok ? acc[mi][ni][v]*SCALE2INV : PADVAL);
            }
        }
    __syncthreads();
    {
        __half* tileD = P + (size_t)(b*4 + kind)*TSZ + ((size_t)bx*12 + by)*TILE;
        #pragma unroll
        for (int it = 0; it < 8; ++it){
            int e = it*256 + tid;
            int r = e >> 4, q = e & 15;
            *(uint4*)(tileD + r*128 + q*8) = *(const uint4*)(ldsO + r*136 + q*8);
        }
    }
    // ---- transposed tile ----
    if (kind == 0 || bx != by){
        __syncthreads();
        #pragma unroll
        for (int mi = 0; mi < 4; ++mi)
            #pragma unroll
            for (int ni = 0; ni < 4; ++ni){
                int trow = wn + ni*16 + lr;
                #pragma unroll
                for (int v = 0; v < 4; ++v){
                    int tcol = wm + mi*16 + cq*4 + v;
                    bool rowok = (row0 + tcol) < NP;   // orig row -> T col mask
                    ldsO[trow*136 + tcol] = __float2half(rowok ? acc[mi][ni][v]*SCALE2INV : PADVAL);
                }
            }
        __syncthreads();
        int slotT = (kind == 0) ? 1 : kind;
        __half* tileT = P + (size_t)(b*4 + slotT)*TSZ + ((size_t)by*12 + bx)*TILE;
        #pragma unroll
        for (int it = 0; it < 8; ++it){
            int e = it*256 + tid;
            int r = e >> 4, q = e & 15;
            *(uint4*)(tileT + r*128 + q*8) = *(const uint4*)(ldsO + r*136 + q*8);
        }
    }
}

// ---- persistent Sinkhorn ----
__device__ __forceinline__ float rowmin192(const __half* __restrict__ rowb,
                                           const float4* __restrict__ a4, int lane){
    float m = 3.0e38f;
    #pragma unroll
    for (int it = 0; it < 3; ++it){
        int c = lane + it*64;              // 0..191
        int tt = c >> 4, q = c & 15;
        const uint4 pk = *(const uint4*)(rowb + (size_t)tt*TILE + q*8);
        float4 a0 = a4[tt*32 + q*2];
        float4 a1 = a4[tt*32 + q*2 + 1];
        float2 c0 = __half22float2(*(const __half2*)&pk.x);
        float2 c1 = __half22float2(*(const __half2*)&pk.y);
        float2 c2 = __half22float2(*(const __half2*)&pk.z);
        float2 c3 = __half22float2(*(const __half2*)&pk.w);
        m = fminf(m, fminf(fminf(a0.x - c0.x, a0.y - c0.y), fminf(a0.z - c1.x, a0.w - c1.y)));
        m = fminf(m, fminf(fminf(a1.x - c2.x, a1.y - c2.y), fminf(a1.z - c3.x, a1.w - c3.y)));
    }
    #pragma unroll
    for (int o = 1; o < 64; o <<= 1) m = fminf(m, __shfl_xor(m, o, 64));
    return m;
}

__device__ __forceinline__ void gbar(int* bars, int k){
    __syncthreads();
    if (threadIdx.x == 0){
        __hip_atomic_fetch_add(&bars[k], 1, __ATOMIC_RELEASE, __HIP_MEMORY_SCOPE_AGENT);
        while (__hip_atomic_load(&bars[k], __ATOMIC_ACQUIRE, __HIP_MEMORY_SCOPE_AGENT) < NBLK)
            __builtin_amdgcn_s_sleep(8);
    }
    __syncthreads();
}

__global__ __launch_bounds__(256, 2) void k_sink(const __half* __restrict__ P,
        float* fs, float* uvv, float* px0, float* px1, float* py0, float* py1,
        int* bars, int* flags){
    int tid = threadIdx.x;
    int lane = tid & 63;
    int gwave = (int)blockIdx.x*4 + (tid >> 6);
    const int NW = NBLK*4;
    __shared__ int s_ch[2];
    float* pxA = px0; float* pxB = px1;
    float* pyA = py0; float* pyB = py1;
    bool otF = false, pxF = false, pyF = false;

    for (int t = 0; t < 30; ++t){
        // ---------- phase A: fs (kind0, from u) ; psxx (kind2) ----------
        if (tid < 2) s_ch[tid] = 0;
        __syncthreads();
        int ch0 = 0, ch1 = 0;
        if (!otF){
            for (int r = gwave; r < NB*NP; r += NW){
                int b = r/NP, i = r - b*NP;
                const __half* rowb = P + (size_t)(b*4 + 0)*TSZ + (size_t)(i>>7)*12*TILE + (size_t)(i&127)*128;
                float m = rowmin192(rowb, (const float4*)(uvv + b*VSZ), lane);
                if (lane == 0){
                    float nv = -(m + KADD);
                    int o = b*VSZ + i;
                    if (__float_as_uint(nv) != __float_as_uint(fs[o])) ch0 = 1;
                    fs[o] = nv;
                }
            }
        }
        if (!pxF){
            for (int r = gwave; r < NB*NP; r += NW){
                int b = r/NP, i = r - b*NP;
                const __half* rowb = P + (size_t)(b*4 + 2)*TSZ + (size_t)(i>>7)*12*TILE + (size_t)(i&127)*128;
                float m = rowmin192(rowb, (const float4*)(pxA + b*VSZ), lane);
                if (lane == 0){
                    int o = b*VSZ + i;
                    float nv = 0.5f*(pxA[o] - m - KADD);
                    if (__float_as_uint(nv) != __float_as_uint(pxA[o])) ch1 = 1;
                    pxB[o] = nv;
                }
            }
        }
        if (ch0) s_ch[0] = 1;
        if (ch1) s_ch[1] = 1;
        __syncthreads();
        if (tid == 0){
            if (s_ch[0]) atomicOr(&flags[4*t + 0], 1);
            if (s_ch[1]) atomicOr(&flags[4*t + 1], 1);
        }
        gbar(bars, 2*t);
        // ---------- phase B: u (kind1, from fs) ; psyy (kind3) ----------
        if (tid < 2) s_ch[tid] = 0;
        __syncthreads();
        ch0 = 0; ch1 = 0;
        if (!otF){
            for (int r = gwave; r < NB*NP; r += NW){
                int b = r/NP, i = r - b*NP;
                const __half* rowb = P + (size_t)(b*4 + 1)*TSZ + (size_t)(i>>7)*12*TILE + (size_t)(i&127)*128;
                float m = rowmin192(rowb, (const float4*)(fs + b*VSZ), lane);
                if (lane == 0){
                    float nv = -(m + KADD);
                    int o = b*VSZ + i;
                    if (__float_as_uint(nv) != __float_as_uint(uvv[o])) ch0 = 1;
                    uvv[o] = nv;
                }
            }
        }
        if (!pyF){
            for (int r = gwave; r < NB*NP; r += NW){
                int b = r/NP, i = r - b*NP;
                const __half* rowb = P + (size_t)(b*4 + 3)*TSZ + (size_t)(i>>7)*12*TILE + (size_t)(i&127)*128;
                float m = rowmin192(rowb, (const float4*)(pyA + b*VSZ), lane);
                if (lane == 0){
                    int o = b*VSZ + i;
                    float nv = 0.5f*(pyA[o] - m - KADD);
                    if (__float_as_uint(nv) != __float_as_uint(pyA[o])) ch1 = 1;
                    pyB[o] = nv;
                }
            }
        }
        if (ch0) s_ch[0] = 1;
        if (ch1) s_ch[1] = 1;
        __syncthreads();
        if (tid == 0){
            if (s_ch[0]) atomicOr(&flags[4*t + 2], 1);
            if (s_ch[1]) atomicOr(&flags[4*t + 3], 1);
        }
        gbar(bars, 2*t + 1);
        // ---------- freeze evaluation (uniform across grid) ----------
        int fFS = __hip_atomic_load(&flags[4*t + 0], __ATOMIC_RELAXED, __HIP_MEMORY_SCOPE_AGENT);
        int fPX = __hip_atomic_load(&flags[4*t + 1], __ATOMIC_RELAXED, __HIP_MEMORY_SCOPE_AGENT);
        int fU  = __hip_atomic_load(&flags[4*t + 2], __ATOMIC_RELAXED, __HIP_MEMORY_SCOPE_AGENT);
        int fPY = __hip_atomic_load(&flags[4*t + 3], __ATOMIC_RELAXED, __HIP_MEMORY_SCOPE_AGENT);
        if (!otF && fFS == 0 && fU == 0) otF = true;
        if (!pxF && fPX == 0) pxF = true;
        if (!pyF && fPY == 0) pyF = true;
        { float* tmp = pxA; pxA = pxB; pxB = tmp; tmp = pyA; pyA = pyB; pyB = tmp; }
        if (otF && pxF && pyF) break;
    }
    // canonicalize final ps buffers into px0/py0 for k_final
    for (int idx = (int)blockIdx.x*256 + tid; idx < NB*VSZ; idx += NBLK*256){
        if (pxA != px0) px0[idx] = pxA[idx];
        if (pyA != py0) py0[idx] = pyA[idx];
    }
}

// S = (4/1500) * sum_b,i (psxx + psyy - fs - u)
__global__ void k_final(const float* __restrict__ fs, const float* __restrict__ u,
                        const float* __restrict__ psxx, const float* __restrict__ psyy,
                        float* __restrict__ out){
    __shared__ double red[256];
    double s = 0.0;
    for (int t = threadIdx.x; t < NB*NP; t += 256){
        int b = t / NP, i = t - b*NP; int o = b*VSZ + i;
        s += (double)psxx[o] + (double)psyy[o] - (double)fs[o] - (double)u[o];
    }
    red[threadIdx.x] = s; __syncthreads();
    for (int w = 128; w > 0; w >>= 1){
        if (threadIdx.x < w) red[threadIdx.x] += red[threadIdx.x + w];
        __syncthreads();
    }
    if (threadIdx.x == 0) out[0] = (float)(red[0] * (4.0/1500.0));
}

extern "C" void kernel_launch(void* const* d_in, const int* in_sizes, int n_in,
                              void* d_out, int out_size, void* d_ws, size_t ws_size,
                              hipStream_t stream) {
    const float* x = (const float*)d_in[0];
    const float* y = (const float*)d_in[1];
    float* out = (float*)d_out;

    __half* pxh = (__half*)d_ws;                       // NB*NP*DP halfs
    __half* pyh = pxh + (size_t)NB*NP*DP;
    float* F   = (float*)(pyh + (size_t)NB*NP*DP);     // byte offset 7,680,000
    float* csx = F;
    float* csy = csx + NB*DD;
    float* fs  = csy + NB*DD;
    float* uv  = fs + NB*VSZ;
    float* px0 = uv + NB*VSZ;
    float* px1 = px0 + NB*VSZ;
    float* py0 = px1 + NB*VSZ;
    float* py1 = py0 + NB*VSZ;
    int* bars  = (int*)(py1 + NB*VSZ);                 // 64 ints
    int* flags = bars + 64;                            // 128 ints
    float* partial = (float*)(flags + 128);            // 12*NB*2*DD floats
    float* smallEnd = partial + (size_t)12*NB*2*DD;
    size_t pOff = (((size_t)((char*)smallEnd - (char*)d_ws)) + 255) & ~(size_t)255;
    __half* P = (__half*)((char*)d_ws + pOff);         // 16*TSZ halfs = 75.5 MB

    // zero: csx..flags (39,456 4-byte words; bars/flags are bit-zero too)
    int nzero = (int)(((float*)(flags + 128)) - csx);
    k_zero<<<(nzero + 255)/256, 256, 0, stream>>>(csx, nzero);

    k_colsum_p1<<<dim3(12, NB, 2), 256, 0, stream>>>(x, y, partial);
    k_colsum_p2<<<10, 256, 0, stream>>>(partial, csx, csy);

    k_normrow<<<dim3(NP, NB, 2), 256, 0, stream>>>(x, y, csx, csy, pxh, pyh, px0, uv, py0);

    k_gemm_mfma<<<dim3(12, 12, 12), 256, 0, stream>>>(pxh, pyh, P);

    k_sink<<<NBLK, 256, 0, stream>>>(P, fs, uv, px0, px1, py0, py1, bars, flags);

    k_final<<<1, 256, 0, stream>>>(fs, uv, px0, py0, out);
}

// Round 10
// 290.571 us; speedup vs baseline: 2.9007x; 1.6579x over previous
//
// v7 — k_sink split into 12 independent block-groups (4 OT x 48 blks, 8 self x 40 blks),
// group-local barriers, register-hoisted vector slices. GEMM/pre/post unchanged from v6.
#include <hip/hip_runtime.h>
#include <hip/hip_fp16.h>

#define NP 1500
#define DD 300
#define DP 320              // padded dims (mult of 32)
#define VSZ 1536            // vector stride per batch (floats)
#define NB 4
#define TILE 16384          // halfs per 128x128 tile
#define TSZ (1536*1536)     // halfs per P slot
#define OTB 48              // blocks per OT group
#define SELFB 40            // blocks per self group
#define KADD 1.8283051e-8f  // eps * ln(1500), eps = (5e-5)^2
#define PADVAL (-60000.0f)
#define SCALE 256.0f
#define SCALE2INV (1.0f/65536.0f)

typedef _Float16 f16x8 __attribute__((ext_vector_type(8)));
typedef float f32x4 __attribute__((ext_vector_type(4)));

__global__ void k_zero(float* p, int n){
    int i = blockIdx.x*blockDim.x + threadIdx.x;
    if (i < n) p[i] = 0.f;
}

// ---- deterministic column sums (2-stage, no float atomics) ----
__global__ __launch_bounds__(256) void k_colsum_p1(const float* __restrict__ x, const float* __restrict__ y,
                                                   float* __restrict__ partial){
    int rc = blockIdx.x, b = blockIdx.y, src = blockIdx.z;
    const float* in = (src ? y : x) + ((size_t)b*NP + rc*125)*DD;
    int tid = threadIdx.x;
    float s0 = 0.f, s1 = 0.f;
    #pragma unroll 4
    for (int r = 0; r < 125; ++r){
        float v0 = in[r*DD + tid];
        s0 = fmaf(v0, v0, s0);
        if (tid < 44){
            float v1 = in[r*DD + 256 + tid];
            s1 = fmaf(v1, v1, s1);
        }
    }
    float* po = partial + (((size_t)rc*NB + b)*2 + src)*DD;
    po[tid] = s0;
    if (tid < 44) po[256 + tid] = s1;
}

__global__ void k_colsum_p2(const float* __restrict__ partial,
                            float* __restrict__ csx, float* __restrict__ csy){
    int idx = blockIdx.x*256 + threadIdx.x;
    if (idx >= NB*2*DD) return;
    int c = idx % DD; int t = idx / DD; int src = t & 1; int b = t >> 1;
    float s = 0.f;
    #pragma unroll
    for (int rc = 0; rc < 12; ++rc)
        s += partial[(((size_t)rc*NB + b)*2 + src)*DD + c];
    (src ? csy : csx)[b*DD + c] = s;
}

// ---- fused normalize (fp16, scaled) + row-norm init of small vectors ----
__global__ __launch_bounds__(256) void k_normrow(const float* __restrict__ x, const float* __restrict__ y,
        const float* __restrict__ csx, const float* __restrict__ csy,
        __half* __restrict__ pxh, __half* __restrict__ pyh,
        float* __restrict__ psxx0, float* __restrict__ uvv, float* __restrict__ psyy0){
    int i = blockIdx.x, b = blockIdx.y, src = blockIdx.z;
    const float* in = (src ? y : x) + ((size_t)b*NP + i)*DD;
    const float* cs = (src ? csy : csx) + b*DD;
    __half* oph = (src ? pyh : pxh) + ((size_t)b*NP + i)*DP;
    int tid = threadIdx.x;
    float s;
    {
        float u = in[tid];
        float vu = u*u / cs[tid];
        oph[tid] = __float2half(vu * SCALE);
        s = vu*vu;
    }
    if (tid < 64){
        int c = 256 + tid;
        float h = 0.f, vu = 0.f;
        if (c < DD){
            float u = in[c];
            vu = u*u / cs[c];
            h = vu * SCALE;
        }
        oph[c] = __float2half(h);
        s += vu*vu;
    }
    #pragma unroll
    for (int o2 = 1; o2 < 64; o2 <<= 1) s += __shfl_xor(s, o2, 64);
    __shared__ float sred[4];
    if ((tid & 63) == 0) sred[tid>>6] = s;
    __syncthreads();
    if (tid == 0){
        float val = 0.5f*(sred[0]+sred[1]+sred[2]+sred[3]);
        int o = b*VSZ + i;
        if (src){ uvv[o] = val; psyy0[o] = val; }
        else    { psxx0[o] = val; }
    }
}

// ---- MFMA GEMM, tiled-P output, triangle + transpose-write (unchanged from v6) ----
__global__ __launch_bounds__(256) void k_gemm_mfma(const __half* __restrict__ pxh,
                                                   const __half* __restrict__ pyh,
                                                   __half* __restrict__ P){
    int z = blockIdx.z; int b = z/3; int kidx = z - b*3;
    int kind = (kidx==0) ? 0 : ((kidx==1) ? 2 : 3);
    int bx = blockIdx.x, by = blockIdx.y;
    if (kind != 0 && by > bx) return;
    const __half* A = (((kind==0)||(kind==2)) ? pxh : pyh) + (size_t)b*NP*DP;
    const __half* B = (((kind==0)||(kind==3)) ? pyh : pxh) + (size_t)b*NP*DP;

    __shared__ __align__(16) char smem[128*136*2];
    char* ldsA = smem;
    char* ldsB = smem + 8192;
    __half* ldsO = (__half*)smem;

    int tid = threadIdx.x;
    int row0 = bx*128, col0 = by*128;
    int lane = tid & 63;
    int w = tid >> 6;
    int wm = (w >> 1)*64, wn = (w & 1)*64;
    int g = tid & 3, rr = tid >> 2;
    int swst = ((g ^ (rr & 3)) << 4);
    int lr = lane & 15;
    int sw = (((lane >> 4) ^ (lane & 3)) << 4);

    f32x4 acc[4][4];
    #pragma unroll
    for (int mi = 0; mi < 4; ++mi)
        #pragma unroll
        for (int ni = 0; ni < 4; ++ni)
            acc[mi][ni] = (f32x4){0.f, 0.f, 0.f, 0.f};

    for (int k0 = 0; k0 < DP; k0 += 32){
        uint4 va[2], vb[2];
        #pragma unroll
        for (int rd = 0; rd < 2; ++rd){
            int r = rr + rd*64;
            int ar = row0 + r; if (ar > NP-1) ar = NP-1;
            int br = col0 + r; if (br > NP-1) br = NP-1;
            va[rd] = *(const uint4*)(A + (size_t)ar*DP + k0 + g*8);
            vb[rd] = *(const uint4*)(B + (size_t)br*DP + k0 + g*8);
        }
        __syncthreads();
        #pragma unroll
        for (int rd = 0; rd < 2; ++rd){
            int r = rr + rd*64;
            *(uint4*)(ldsA + r*64 + swst) = va[rd];
            *(uint4*)(ldsB + r*64 + swst) = vb[rd];
        }
        __syncthreads();
        f16x8 av[4], bv[4];
        #pragma unroll
        for (int mi = 0; mi < 4; ++mi)
            av[mi] = *(const f16x8*)(ldsA + (wm + mi*16 + lr)*64 + sw);
        #pragma unroll
        for (int ni = 0; ni < 4; ++ni)
            bv[ni] = *(const f16x8*)(ldsB + (wn + ni*16 + lr)*64 + sw);
        #pragma unroll
        for (int mi = 0; mi < 4; ++mi)
            #pragma unroll
            for (int ni = 0; ni < 4; ++ni)
                acc[mi][ni] = __builtin_amdgcn_mfma_f32_16x16x32_f16(av[mi], bv[ni], acc[mi][ni], 0, 0, 0);
    }

    int cq = lane >> 4;
    __syncthreads();
    #pragma unroll
    for (int mi = 0; mi < 4; ++mi)
        #pragma unroll
        for (int ni = 0; ni < 4; ++ni){
            int lcol = wn + ni*16 + lr;
            bool colok = (col0 + lcol) < NP;
            #pragma unroll
            for (int v = 0; v < 4; ++v){
                int lrow = wm + mi*16 + cq*4 + v;
                ldsO[lrow*136 + lcol] = __float2half(colok ? acc[mi][ni][v]*SCALE2INV : PADVAL);
            }
        }
    __syncthreads();
    {
        __half* tileD = P + (size_t)(b*4 + kind)*TSZ + ((size_t)bx*12 + by)*TILE;
        #pragma unroll
        for (int it = 0; it < 8; ++it){
            int e = it*256 + tid;
            int r = e >> 4, q = e & 15;
            *(uint4*)(tileD + r*128 + q*8) = *(const uint4*)(ldsO + r*136 + q*8);
        }
    }
    if (kind == 0 || bx != by){
        __syncthreads();
        #pragma unroll
        for (int mi = 0; mi < 4; ++mi)
            #pragma unroll
            for (int ni = 0; ni < 4; ++ni){
                int trow = wn + ni*16 + lr;
                #pragma unroll
                for (int v = 0; v < 4; ++v){
                    int tcol = wm + mi*16 + cq*4 + v;
                    bool rowok = (row0 + tcol) < NP;
                    ldsO[trow*136 + tcol] = __float2half(rowok ? acc[mi][ni][v]*SCALE2INV : PADVAL);
                }
            }
        __syncthreads();
        int slotT = (kind == 0) ? 1 : kind;
        __half* tileT = P + (size_t)(b*4 + slotT)*TSZ + ((size_t)by*12 + bx)*TILE;
        #pragma unroll
        for (int it = 0; it < 8; ++it){
            int e = it*256 + tid;
            int r = e >> 4, q = e & 15;
            *(uint4*)(tileT + r*128 + q*8) = *(const uint4*)(ldsO + r*136 + q*8);
        }
    }
}

// ---- persistent Sinkhorn, 12 independent block-groups ----
__device__ __forceinline__ void groupbar(int* slot, int gsz){
    __syncthreads();
    if (threadIdx.x == 0){
        __hip_atomic_fetch_add(slot, 1, __ATOMIC_RELEASE, __HIP_MEMORY_SCOPE_AGENT);
        while (__hip_atomic_load(slot, __ATOMIC_ACQUIRE, __HIP_MEMORY_SCOPE_AGENT) < gsz)
            __builtin_amdgcn_s_sleep(4);
    }
    __syncthreads();
}

// row-min over 1536 cols with vector slice pre-loaded in regs (A0/A1 per 64-col chunk)
__device__ __forceinline__ float rowmin_h(const __half* __restrict__ rowb,
                                          const float4* A0, const float4* A1, int lane){
    float m = 3.0e38f;
    #pragma unroll
    for (int it = 0; it < 3; ++it){
        int c = lane + it*64;
        int tt = c >> 4, q = c & 15;
        const uint4 pk = *(const uint4*)(rowb + (size_t)tt*TILE + q*8);
        float2 c0 = __half22float2(*(const __half2*)&pk.x);
        float2 c1 = __half22float2(*(const __half2*)&pk.y);
        float2 c2 = __half22float2(*(const __half2*)&pk.z);
        float2 c3 = __half22float2(*(const __half2*)&pk.w);
        m = fminf(m, fminf(fminf(A0[it].x - c0.x, A0[it].y - c0.y), fminf(A0[it].z - c1.x, A0[it].w - c1.y)));
        m = fminf(m, fminf(fminf(A1[it].x - c2.x, A1[it].y - c2.y), fminf(A1[it].z - c3.x, A1[it].w - c3.y)));
    }
    #pragma unroll
    for (int o = 1; o < 64; o <<= 1) m = fminf(m, __shfl_xor(m, o, 64));
    return m;
}

__device__ __forceinline__ void loadvec(const float* v, float4* A0, float4* A1, int lane){
    const float4* a4 = (const float4*)v;
    #pragma unroll
    for (int it = 0; it < 3; ++it){
        int c = lane + it*64, tt = c >> 4, q = c & 15;
        A0[it] = a4[tt*32 + q*2];
        A1[it] = a4[tt*32 + q*2 + 1];
    }
}

__global__ __launch_bounds__(256, 2) void k_sink(const __half* __restrict__ P,
        float* fs, float* uvv, float* px0, float* px1, float* py0, float* py1,
        int* bars, int* flags){
    int tid = threadIdx.x;
    int lane = tid & 63;
    int wid = tid >> 6;
    int blk = (int)blockIdx.x;
    __shared__ int s_ch0, s_ch1;
    float4 A0[3], A1[3];

    if (blk < 4*OTB){
        // ---------------- OT group (fs <-> u), batch b ----------------
        int b = blk / OTB, lb = blk - b*OTB;
        int gw = lb*4 + wid;
        const int NWV = OTB*4;
        int* gbarp  = bars + b*64;
        int* gflagp = flags + b*64;
        const __half* P0 = P + (size_t)(b*4 + 0)*TSZ;
        const __half* P1 = P + (size_t)(b*4 + 1)*TSZ;
        float* fsb = fs + b*VSZ;
        float* uvb = uvv + b*VSZ;
        for (int t = 0; t < 30; ++t){
            // phase A: fs_i = -(min_j(u_j - P0_ij) + K)
            if (tid == 0) s_ch0 = 0;
            __syncthreads();
            {
                int ch = 0;
                loadvec(uvb, A0, A1, lane);
                for (int i = gw; i < NP; i += NWV){
                    const __half* rowb = P0 + (size_t)(i>>7)*12*TILE + (size_t)(i&127)*128;
                    float m = rowmin_h(rowb, A0, A1, lane);
                    if (lane == 0){
                        float nv = -(m + KADD);
                        if (__float_as_uint(nv) != __float_as_uint(fsb[i])) ch = 1;
                        fsb[i] = nv;
                    }
                }
                if (ch) s_ch0 = 1;
            }
            __syncthreads();
            if (tid == 0 && s_ch0) atomicOr(&gflagp[2*t], 1);
            groupbar(&gbarp[2*t], OTB);
            // phase B: u_j = -(min_i(fs_i - P1_ji) + K)
            if (tid == 0) s_ch0 = 0;
            __syncthreads();
            {
                int ch = 0;
                loadvec(fsb, A0, A1, lane);
                for (int i = gw; i < NP; i += NWV){
                    const __half* rowb = P1 + (size_t)(i>>7)*12*TILE + (size_t)(i&127)*128;
                    float m = rowmin_h(rowb, A0, A1, lane);
                    if (lane == 0){
                        float nv = -(m + KADD);
                        if (__float_as_uint(nv) != __float_as_uint(uvb[i])) ch = 1;
                        uvb[i] = nv;
                    }
                }
                if (ch) s_ch0 = 1;
            }
            __syncthreads();
            if (tid == 0 && s_ch0) atomicOr(&gflagp[2*t + 1], 1);
            groupbar(&gbarp[2*t + 1], OTB);
            int fA = __hip_atomic_load(&gflagp[2*t],     __ATOMIC_RELAXED, __HIP_MEMORY_SCOPE_AGENT);
            int fB = __hip_atomic_load(&gflagp[2*t + 1], __ATOMIC_RELAXED, __HIP_MEMORY_SCOPE_AGENT);
            if (fA == 0 && fB == 0) break;   // frozen: all future iterations identical
        }
    } else {
        // ---------------- self group (psxx or psyy), ping-pong ----------------
        int sg = blk - 4*OTB;
        int g = sg / SELFB, lb = sg - g*SELFB;
        int gw = lb*4 + wid;
        const int NWV = SELFB*4;
        int b = g >> 1, kind = 2 + (g & 1);
        float* bufA = ((g & 1) ? py0 : px0) + b*VSZ;
        float* bufB = ((g & 1) ? py1 : px1) + b*VSZ;
        int* gbarp  = bars + (4 + g)*64;
        int* gflagp = flags + (4 + g)*64;
        const __half* PK = P + (size_t)(b*4 + kind)*TSZ;
        for (int t = 0; t < 30; ++t){
            if (tid == 0) s_ch1 = 0;
            __syncthreads();
            {
                int ch = 0;
                loadvec(bufA, A0, A1, lane);
                for (int i = gw; i < NP; i += NWV){
                    const __half* rowb = PK + (size_t)(i>>7)*12*TILE + (size_t)(i&127)*128;
                    float m = rowmin_h(rowb, A0, A1, lane);
                    if (lane == 0){
                        float ov = bufA[i];
                        float nv = 0.5f*(ov - m - KADD);
                        if (__float_as_uint(nv) != __float_as_uint(ov)) ch = 1;
                        bufB[i] = nv;
                    }
                }
                if (ch) s_ch1 = 1;
            }
            __syncthreads();
            if (tid == 0 && s_ch1) atomicOr(&gflagp[t], 1);
            groupbar(&gbarp[t], SELFB);
            int fC = __hip_atomic_load(&gflagp[t], __ATOMIC_RELAXED, __HIP_MEMORY_SCOPE_AGENT);
            if (fC == 0) break;              // frozen: bufA == bufB bitwise -> px0/py0 valid
            { float* tmp = bufA; bufA = bufB; bufB = tmp; }
        }
        // after 30 full iters (even count) final lands in px0/py0; frozen-break leaves both equal.
    }
}

// S = (4/1500) * sum_b,i (psxx + psyy - fs - u)
__global__ void k_final(const float* __restrict__ fs, const float* __restrict__ u,
                        const float* __restrict__ psxx, const float* __restrict__ psyy,
                        float* __restrict__ out){
    __shared__ double red[256];
    double s = 0.0;
    for (int t = threadIdx.x; t < NB*NP; t += 256){
        int b = t / NP, i = t - b*NP; int o = b*VSZ + i;
        s += (double)psxx[o] + (double)psyy[o] - (double)fs[o] - (double)u[o];
    }
    red[threadIdx.x] = s; __syncthreads();
    for (int w = 128; w > 0; w >>= 1){
        if (threadIdx.x < w) red[threadIdx.x] += red[threadIdx.x + w];
        __syncthreads();
    }
    if (threadIdx.x == 0) out[0] = (float)(red[0] * (4.0/1500.0));
}

extern "C" void kernel_launch(void* const* d_in, const int* in_sizes, int n_in,
                              void* d_out, int out_size, void* d_ws, size_t ws_size,
                              hipStream_t stream) {
    const float* x = (const float*)d_in[0];
    const float* y = (const float*)d_in[1];
    float* out = (float*)d_out;

    __half* pxh = (__half*)d_ws;                       // NB*NP*DP halfs
    __half* pyh = pxh + (size_t)NB*NP*DP;
    float* csx = (float*)(pyh + (size_t)NB*NP*DP);
    float* csy = csx + NB*DD;
    float* fs  = csy + NB*DD;
    float* uv  = fs + NB*VSZ;
    float* px0 = uv + NB*VSZ;
    float* px1 = px0 + NB*VSZ;
    float* py0 = px1 + NB*VSZ;
    float* py1 = py0 + NB*VSZ;
    int* bars  = (int*)(py1 + NB*VSZ);                 // 12*64 ints
    int* flags = bars + 12*64;                         // 12*64 ints
    float* partial = (float*)(flags + 12*64);          // 12*NB*2*DD floats
    float* smallEnd = partial + (size_t)12*NB*2*DD;
    size_t pOff = (((size_t)((char*)smallEnd - (char*)d_ws)) + 255) & ~(size_t)255;
    __half* P = (__half*)((char*)d_ws + pOff);         // 16*TSZ halfs = 75.5 MB

    // zero: csx .. flags end (partial is fully overwritten by colsum_p1)
    int nzero = (int)(((float*)(flags + 12*64)) - csx);
    k_zero<<<(nzero + 255)/256, 256, 0, stream>>>(csx, nzero);

    k_colsum_p1<<<dim3(12, NB, 2), 256, 0, stream>>>(x, y, partial);
    k_colsum_p2<<<10, 256, 0, stream>>>(partial, csx, csy);

    k_normrow<<<dim3(NP, NB, 2), 256, 0, stream>>>(x, y, csx, csy, pxh, pyh, px0, uv, py0);

    k_gemm_mfma<<<dim3(12, 12, 12), 256, 0, stream>>>(pxh, pyh, P);

    k_sink<<<4*OTB + 8*SELFB, 256, 0, stream>>>(P, fs, uv, px0, px1, py0, py1, bars, flags);

    k_final<<<1, 256, 0, stream>>>(fs, uv, px0, py0, out);
}

// Round 11
// 281.555 us; speedup vs baseline: 2.9936x; 1.0320x over previous
//
// v8 — GEMM: BK=64 + register prefetch + XOR-swizzled LDS (10 barriers/block);
// k_sink: __restrict__ + 2-row load pipelining. Groups/barriers/freeze unchanged from v7.
#include <hip/hip_runtime.h>
#include <hip/hip_fp16.h>

#define NP 1500
#define DD 300
#define DP 320              // padded dims (mult of 64 for BK=64 steps)
#define VSZ 1536            // vector stride per batch (floats)
#define NB 4
#define TILE 16384          // halfs per 128x128 tile
#define TSZ (1536*1536)     // halfs per P slot
#define OTB 48              // blocks per OT group
#define SELFB 40            // blocks per self group
#define KADD 1.8283051e-8f  // eps * ln(1500), eps = (5e-5)^2
#define PADVAL (-60000.0f)
#define SCALE 256.0f
#define SCALE2INV (1.0f/65536.0f)

typedef _Float16 f16x8 __attribute__((ext_vector_type(8)));
typedef float f32x4 __attribute__((ext_vector_type(4)));

__global__ void k_zero(float* p, int n){
    int i = blockIdx.x*blockDim.x + threadIdx.x;
    if (i < n) p[i] = 0.f;
}

// ---- deterministic column sums (2-stage, no float atomics) ----
__global__ __launch_bounds__(256) void k_colsum_p1(const float* __restrict__ x, const float* __restrict__ y,
                                                   float* __restrict__ partial){
    int rc = blockIdx.x, b = blockIdx.y, src = blockIdx.z;
    const float* in = (src ? y : x) + ((size_t)b*NP + rc*125)*DD;
    int tid = threadIdx.x;
    float s0 = 0.f, s1 = 0.f;
    #pragma unroll 4
    for (int r = 0; r < 125; ++r){
        float v0 = in[r*DD + tid];
        s0 = fmaf(v0, v0, s0);
        if (tid < 44){
            float v1 = in[r*DD + 256 + tid];
            s1 = fmaf(v1, v1, s1);
        }
    }
    float* po = partial + (((size_t)rc*NB + b)*2 + src)*DD;
    po[tid] = s0;
    if (tid < 44) po[256 + tid] = s1;
}

__global__ void k_colsum_p2(const float* __restrict__ partial,
                            float* __restrict__ csx, float* __restrict__ csy){
    int idx = blockIdx.x*256 + threadIdx.x;
    if (idx >= NB*2*DD) return;
    int c = idx % DD; int t = idx / DD; int src = t & 1; int b = t >> 1;
    float s = 0.f;
    #pragma unroll
    for (int rc = 0; rc < 12; ++rc)
        s += partial[(((size_t)rc*NB + b)*2 + src)*DD + c];
    (src ? csy : csx)[b*DD + c] = s;
}

// ---- fused normalize (fp16, scaled) + row-norm init of small vectors ----
__global__ __launch_bounds__(256) void k_normrow(const float* __restrict__ x, const float* __restrict__ y,
        const float* __restrict__ csx, const float* __restrict__ csy,
        __half* __restrict__ pxh, __half* __restrict__ pyh,
        float* __restrict__ psxx0, float* __restrict__ uvv, float* __restrict__ psyy0){
    int i = blockIdx.x, b = blockIdx.y, src = blockIdx.z;
    const float* in = (src ? y : x) + ((size_t)b*NP + i)*DD;
    const float* cs = (src ? csy : csx) + b*DD;
    __half* oph = (src ? pyh : pxh) + ((size_t)b*NP + i)*DP;
    int tid = threadIdx.x;
    float s;
    {
        float u = in[tid];
        float vu = u*u / cs[tid];
        oph[tid] = __float2half(vu * SCALE);
        s = vu*vu;
    }
    if (tid < 64){
        int c = 256 + tid;
        float h = 0.f, vu = 0.f;
        if (c < DD){
            float u = in[c];
            vu = u*u / cs[c];
            h = vu * SCALE;
        }
        oph[c] = __float2half(h);
        s += vu*vu;
    }
    #pragma unroll
    for (int o2 = 1; o2 < 64; o2 <<= 1) s += __shfl_xor(s, o2, 64);
    __shared__ float sred[4];
    if ((tid & 63) == 0) sred[tid>>6] = s;
    __syncthreads();
    if (tid == 0){
        float val = 0.5f*(sred[0]+sred[1]+sred[2]+sred[3]);
        int o = b*VSZ + i;
        if (src){ uvv[o] = val; psyy0[o] = val; }
        else    { psxx0[o] = val; }
    }
}

// ---- MFMA GEMM: BK=64, register prefetch, XOR-swizzled LDS, triangle+transpose ----
__global__ __launch_bounds__(256) void k_gemm_mfma(const __half* __restrict__ pxh,
                                                   const __half* __restrict__ pyh,
                                                   __half* __restrict__ P){
    int z = blockIdx.z; int b = z/3; int kidx = z - b*3;
    int kind = (kidx==0) ? 0 : ((kidx==1) ? 2 : 3);
    int bx = blockIdx.x, by = blockIdx.y;
    if (kind != 0 && by > bx) return;
    const __half* A = (((kind==0)||(kind==2)) ? pxh : pyh) + (size_t)b*NP*DP;
    const __half* B = (((kind==0)||(kind==3)) ? pyh : pxh) + (size_t)b*NP*DP;

    __shared__ __align__(16) char smem[128*136*2];   // 34816B; K-loop uses 32KB
    char* ldsA = smem;                  // 128 rows x 64 halfs (128B/row)
    char* ldsB = smem + 16384;
    __half* ldsO = (__half*)smem;       // epilogue: 128 x 136 halfs

    int tid = threadIdx.x;
    int row0 = bx*128, col0 = by*128;
    int lane = tid & 63;
    int w = tid >> 6;
    int wm = (w >> 1)*64, wn = (w & 1)*64;
    int g8 = tid & 7, rw = tid >> 3;     // staging: chunk (8B halfs=16B), row base (0..31)
    int lr = lane & 15, cq = lane >> 4;

    f32x4 acc[4][4];
    #pragma unroll
    for (int mi = 0; mi < 4; ++mi)
        #pragma unroll
        for (int ni = 0; ni < 4; ++ni)
            acc[mi][ni] = (f32x4){0.f, 0.f, 0.f, 0.f};

    uint4 va[4], vb[4];
    #pragma unroll
    for (int is = 0; is < 4; ++is){      // prologue: K-step 0
        int r = rw + is*32;
        int ar = row0 + r; if (ar > NP-1) ar = NP-1;
        int br = col0 + r; if (br > NP-1) br = NP-1;
        va[is] = *(const uint4*)(A + (size_t)ar*DP + g8*8);
        vb[is] = *(const uint4*)(B + (size_t)br*DP + g8*8);
    }
    #pragma unroll
    for (int ks = 0; ks < 5; ++ks){
        if (ks) __syncthreads();
        #pragma unroll
        for (int is = 0; is < 4; ++is){
            int r = rw + is*32;
            int pc = g8 ^ (r & 7);
            *(uint4*)(ldsA + r*128 + pc*16) = va[is];
            *(uint4*)(ldsB + r*128 + pc*16) = vb[is];
        }
        __syncthreads();
        if (ks < 4){
            int k0 = (ks + 1)*64;
            #pragma unroll
            for (int is = 0; is < 4; ++is){
                int r = rw + is*32;
                int ar = row0 + r; if (ar > NP-1) ar = NP-1;
                int br = col0 + r; if (br > NP-1) br = NP-1;
                va[is] = *(const uint4*)(A + (size_t)ar*DP + k0 + g8*8);
                vb[is] = *(const uint4*)(B + (size_t)br*DP + k0 + g8*8);
            }
        }
        f16x8 av[2][4], bv[2][4];
        #pragma unroll
        for (int ksl = 0; ksl < 2; ++ksl){
            int lc = ksl*4 + cq;
            int pc = (lc ^ (lr & 7))*16;
            #pragma unroll
            for (int mi = 0; mi < 4; ++mi)
                av[ksl][mi] = *(const f16x8*)(ldsA + (wm + mi*16 + lr)*128 + pc);
            #pragma unroll
            for (int ni = 0; ni < 4; ++ni)
                bv[ksl][ni] = *(const f16x8*)(ldsB + (wn + ni*16 + lr)*128 + pc);
        }
        #pragma unroll
        for (int ksl = 0; ksl < 2; ++ksl)
            #pragma unroll
            for (int mi = 0; mi < 4; ++mi)
                #pragma unroll
                for (int ni = 0; ni < 4; ++ni)
                    acc[mi][ni] = __builtin_amdgcn_mfma_f32_16x16x32_f16(av[ksl][mi], bv[ksl][ni], acc[mi][ni], 0, 0, 0);
    }

    int cqe = lane >> 4;
    __syncthreads();
    #pragma unroll
    for (int mi = 0; mi < 4; ++mi)
        #pragma unroll
        for (int ni = 0; ni < 4; ++ni){
            int lcol = wn + ni*16 + lr;
            bool colok = (col0 + lcol) < NP;
            #pragma unroll
            for (int v = 0; v < 4; ++v){
                int lrow = wm + mi*16 + cqe*4 + v;
                ldsO[lrow*136 + lcol] = __float2half(colok ? acc[mi][ni][v]*SCALE2INV : PADVAL);
            }
        }
    __syncthreads();
    {
        __half* tileD = P + (size_t)(b*4 + kind)*TSZ + ((size_t)bx*12 + by)*TILE;
        #pragma unroll
        for (int it = 0; it < 8; ++it){
            int e = it*256 + tid;
            int r = e >> 4, q = e & 15;
            *(uint4*)(tileD + r*128 + q*8) = *(const uint4*)(ldsO + r*136 + q*8);
        }
    }
    if (kind == 0 || bx != by){
        __syncthreads();
        #pragma unroll
        for (int mi = 0; mi < 4; ++mi)
            #pragma unroll
            for (int ni = 0; ni < 4; ++ni){
                int trow = wn + ni*16 + lr;
                #pragma unroll
                for (int v = 0; v < 4; ++v){
                    int tcol = wm + mi*16 + cqe*4 + v;
                    bool rowok = (row0 + tcol) < NP;
                    ldsO[trow*136 + tcol] = __float2half(rowok ? acc[mi][ni][v]*SCALE2INV : PADVAL);
                }
            }
        __syncthreads();
        int slotT = (kind == 0) ? 1 : kind;
        __half* tileT = P + (size_t)(b*4 + slotT)*TSZ + ((size_t)by*12 + bx)*TILE;
        #pragma unroll
        for (int it = 0; it < 8; ++it){
            int e = it*256 + tid;
            int r = e >> 4, q = e & 15;
            *(uint4*)(tileT + r*128 + q*8) = *(const uint4*)(ldsO + r*136 + q*8);
        }
    }
}

// ---- persistent Sinkhorn, 12 independent block-groups, 2-row pipelined row-mins ----
__device__ __forceinline__ void groupbar(int* slot, int gsz){
    __syncthreads();
    if (threadIdx.x == 0){
        __hip_atomic_fetch_add(slot, 1, __ATOMIC_RELEASE, __HIP_MEMORY_SCOPE_AGENT);
        while (__hip_atomic_load(slot, __ATOMIC_ACQUIRE, __HIP_MEMORY_SCOPE_AGENT) < gsz)
            __builtin_amdgcn_s_sleep(1);
    }
    __syncthreads();
}

__device__ __forceinline__ void loadvec(const float* __restrict__ v, float4* A0, float4* A1, int lane){
    const float4* a4 = (const float4*)v;
    #pragma unroll
    for (int it = 0; it < 3; ++it){
        int c = lane + it*64, tt = c >> 4, q = c & 15;
        A0[it] = a4[tt*32 + q*2];
        A1[it] = a4[tt*32 + q*2 + 1];
    }
}

__device__ __forceinline__ void loadrow(const __half* __restrict__ rowb, int lane, uint4* pk){
    #pragma unroll
    for (int it = 0; it < 3; ++it){
        int c = lane + it*64, tt = c >> 4, q = c & 15;
        pk[it] = *(const uint4*)(rowb + (size_t)tt*TILE + q*8);
    }
}

__device__ __forceinline__ float redrow(const uint4* pk, const float4* A0, const float4* A1, int lane){
    float m = 3.0e38f;
    #pragma unroll
    for (int it = 0; it < 3; ++it){
        float2 c0 = __half22float2(*(const __half2*)&pk[it].x);
        float2 c1 = __half22float2(*(const __half2*)&pk[it].y);
        float2 c2 = __half22float2(*(const __half2*)&pk[it].z);
        float2 c3 = __half22float2(*(const __half2*)&pk[it].w);
        m = fminf(m, fminf(fminf(A0[it].x - c0.x, A0[it].y - c0.y), fminf(A0[it].z - c1.x, A0[it].w - c1.y)));
        m = fminf(m, fminf(fminf(A1[it].x - c2.x, A1[it].y - c2.y), fminf(A1[it].z - c3.x, A1[it].w - c3.y)));
    }
    #pragma unroll
    for (int o = 1; o < 64; o <<= 1) m = fminf(m, __shfl_xor(m, o, 64));
    return m;
}

#define ROWPTR(PK, i) ((PK) + (size_t)((i) >> 7)*12*TILE + (size_t)((i) & 127)*128)

__global__ __launch_bounds__(256, 2) void k_sink(const __half* __restrict__ P,
        float* __restrict__ fs, float* __restrict__ uvv,
        float* __restrict__ px0, float* __restrict__ px1,
        float* __restrict__ py0, float* __restrict__ py1,
        int* __restrict__ bars, int* __restrict__ flags){
    int tid = threadIdx.x;
    int lane = tid & 63;
    int wid = tid >> 6;
    int blk = (int)blockIdx.x;
    __shared__ int s_ch0, s_ch1;
    float4 A0[3], A1[3];
    uint4 pk0[3], pk1[3];

    if (blk < 4*OTB){
        // ---------------- OT group (fs <-> u), batch b ----------------
        int b = blk / OTB, lb = blk - b*OTB;
        int gw = lb*4 + wid;
        const int NWV = OTB*4;
        int* gbarp  = bars + b*64;
        int* gflagp = flags + b*64;
        const __half* P0 = P + (size_t)(b*4 + 0)*TSZ;
        const __half* P1 = P + (size_t)(b*4 + 1)*TSZ;
        float* fsb = fs + b*VSZ;
        float* uvb = uvv + b*VSZ;
        for (int t = 0; t < 30; ++t){
            // phase A: fs_i = -(min_j(u_j - P0_ij) + K)
            if (tid == 0) s_ch0 = 0;
            __syncthreads();
            {
                int ch = 0;
                loadvec(uvb, A0, A1, lane);
                for (int i = gw; i < NP; i += 2*NWV){
                    int i2 = i + NWV;
                    loadrow(ROWPTR(P0, i), lane, pk0);
                    if (i2 < NP) loadrow(ROWPTR(P0, i2), lane, pk1);
                    float m = redrow(pk0, A0, A1, lane);
                    if (lane == 0){
                        float nv = -(m + KADD);
                        if (__float_as_uint(nv) != __float_as_uint(fsb[i])) ch = 1;
                        fsb[i] = nv;
                    }
                    if (i2 < NP){
                        float m2 = redrow(pk1, A0, A1, lane);
                        if (lane == 0){
                            float nv = -(m2 + KADD);
                            if (__float_as_uint(nv) != __float_as_uint(fsb[i2])) ch = 1;
                            fsb[i2] = nv;
                        }
                    }
                }
                if (ch) s_ch0 = 1;
            }
            __syncthreads();
            if (tid == 0 && s_ch0) atomicOr(&gflagp[2*t], 1);
            groupbar(&gbarp[2*t], OTB);
            // phase B: u_j = -(min_i(fs_i - P1_ji) + K)
            if (tid == 0) s_ch0 = 0;
            __syncthreads();
            {
                int ch = 0;
                loadvec(fsb, A0, A1, lane);
                for (int i = gw; i < NP; i += 2*NWV){
                    int i2 = i + NWV;
                    loadrow(ROWPTR(P1, i), lane, pk0);
                    if (i2 < NP) loadrow(ROWPTR(P1, i2), lane, pk1);
                    float m = redrow(pk0, A0, A1, lane);
                    if (lane == 0){
                        float nv = -(m + KADD);
                        if (__float_as_uint(nv) != __float_as_uint(uvb[i])) ch = 1;
                        uvb[i] = nv;
                    }
                    if (i2 < NP){
                        float m2 = redrow(pk1, A0, A1, lane);
                        if (lane == 0){
                            float nv = -(m2 + KADD);
                            if (__float_as_uint(nv) != __float_as_uint(uvb[i2])) ch = 1;
                            uvb[i2] = nv;
                        }
                    }
                }
                if (ch) s_ch0 = 1;
            }
            __syncthreads();
            if (tid == 0 && s_ch0) atomicOr(&gflagp[2*t + 1], 1);
            groupbar(&gbarp[2*t + 1], OTB);
            int fA = __hip_atomic_load(&gflagp[2*t],     __ATOMIC_RELAXED, __HIP_MEMORY_SCOPE_AGENT);
            int fB = __hip_atomic_load(&gflagp[2*t + 1], __ATOMIC_RELAXED, __HIP_MEMORY_SCOPE_AGENT);
            if (fA == 0 && fB == 0) break;
        }
    } else {
        // ---------------- self group (psxx or psyy), ping-pong ----------------
        int sg = blk - 4*OTB;
        int g = sg / SELFB, lb = sg - g*SELFB;
        int gw = lb*4 + wid;
        const int NWV = SELFB*4;
        int b = g >> 1, kind = 2 + (g & 1);
        float* bufA = ((g & 1) ? py0 : px0) + b*VSZ;
        float* bufB = ((g & 1) ? py1 : px1) + b*VSZ;
        int* gbarp  = bars + (4 + g)*64;
        int* gflagp = flags + (4 + g)*64;
        const __half* PK = P + (size_t)(b*4 + kind)*TSZ;
        for (int t = 0; t < 30; ++t){
            if (tid == 0) s_ch1 = 0;
            __syncthreads();
            {
                int ch = 0;
                loadvec(bufA, A0, A1, lane);
                for (int i = gw; i < NP; i += 2*NWV){
                    int i2 = i + NWV;
                    loadrow(ROWPTR(PK, i), lane, pk0);
                    if (i2 < NP) loadrow(ROWPTR(PK, i2), lane, pk1);
                    float m = redrow(pk0, A0, A1, lane);
                    if (lane == 0){
                        float ov = bufA[i];
                        float nv = 0.5f*(ov - m - KADD);
                        if (__float_as_uint(nv) != __float_as_uint(ov)) ch = 1;
                        bufB[i] = nv;
                    }
                    if (i2 < NP){
                        float m2 = redrow(pk1, A0, A1, lane);
                        if (lane == 0){
                            float ov = bufA[i2];
                            float nv = 0.5f*(ov - m2 - KADD);
                            if (__float_as_uint(nv) != __float_as_uint(ov)) ch = 1;
                            bufB[i2] = nv;
                        }
                    }
                }
                if (ch) s_ch1 = 1;
            }
            __syncthreads();
            if (tid == 0 && s_ch1) atomicOr(&gflagp[t], 1);
            groupbar(&gbarp[t], SELFB);
            int fC = __hip_atomic_load(&gflagp[t], __ATOMIC_RELAXED, __HIP_MEMORY_SCOPE_AGENT);
            if (fC == 0) break;              // frozen: bufA == bufB bitwise
            { float* tmp = bufA; bufA = bufB; bufB = tmp; }
        }
        // 30 full iters: last write (t=29, odd) lands in px0/py0; frozen-break leaves both equal.
    }
}

// S = (4/1500) * sum_b,i (psxx + psyy - fs - u)
__global__ void k_final(const float* __restrict__ fs, const float* __restrict__ u,
                        const float* __restrict__ psxx, const float* __restrict__ psyy,
                        float* __restrict__ out){
    __shared__ double red[256];
    double s = 0.0;
    for (int t = threadIdx.x; t < NB*NP; t += 256){
        int b = t / NP, i = t - b*NP; int o = b*VSZ + i;
        s += (double)psxx[o] + (double)psyy[o] - (double)fs[o] - (double)u[o];
    }
    red[threadIdx.x] = s; __syncthreads();
    for (int w = 128; w > 0; w >>= 1){
        if (threadIdx.x < w) red[threadIdx.x] += red[threadIdx.x + w];
        __syncthreads();
    }
    if (threadIdx.x == 0) out[0] = (float)(red[0] * (4.0/1500.0));
}

extern "C" void kernel_launch(void* const* d_in, const int* in_sizes, int n_in,
                              void* d_out, int out_size, void* d_ws, size_t ws_size,
                              hipStream_t stream) {
    const float* x = (const float*)d_in[0];
    const float* y = (const float*)d_in[1];
    float* out = (float*)d_out;

    __half* pxh = (__half*)d_ws;                       // NB*NP*DP halfs
    __half* pyh = pxh + (size_t)NB*NP*DP;
    float* csx = (float*)(pyh + (size_t)NB*NP*DP);
    float* csy = csx + NB*DD;
    float* fs  = csy + NB*DD;
    float* uv  = fs + NB*VSZ;
    float* px0 = uv + NB*VSZ;
    float* px1 = px0 + NB*VSZ;
    float* py0 = px1 + NB*VSZ;
    float* py1 = py0 + NB*VSZ;
    int* bars  = (int*)(py1 + NB*VSZ);                 // 12*64 ints
    int* flags = bars + 12*64;                         // 12*64 ints
    float* partial = (float*)(flags + 12*64);          // 12*NB*2*DD floats
    float* smallEnd = partial + (size_t)12*NB*2*DD;
    size_t pOff = (((size_t)((char*)smallEnd - (char*)d_ws)) + 255) & ~(size_t)255;
    __half* P = (__half*)((char*)d_ws + pOff);         // 16*TSZ halfs = 75.5 MB

    int nzero = (int)(((float*)(flags + 12*64)) - csx);
    k_zero<<<(nzero + 255)/256, 256, 0, stream>>>(csx, nzero);

    k_colsum_p1<<<dim3(12, NB, 2), 256, 0, stream>>>(x, y, partial);
    k_colsum_p2<<<10, 256, 0, stream>>>(partial, csx, csy);

    k_normrow<<<dim3(NP, NB, 2), 256, 0, stream>>>(x, y, csx, csy, pxh, pyh, px0, uv, py0);

    k_gemm_mfma<<<dim3(12, 12, 12), 256, 0, stream>>>(pxh, pyh, P);

    k_sink<<<4*OTB + 8*SELFB, 256, 0, stream>>>(P, fs, uv, px0, px1, py0, py1, bars, flags);

    k_final<<<1, 256, 0, stream>>>(fs, uv, px0, py0, out);
}